// Round 9
// baseline (225.856 us; speedup 1.0000x reference)
//
#include <hip/hip_runtime.h>
#include <hip/hip_bf16.h>
#include <cstdint>
#include <cstddef>

using bf16 = __hip_bfloat16;
typedef __bf16 bf16x8 __attribute__((ext_vector_type(8)));
typedef float f32x4 __attribute__((ext_vector_type(4)));

#define DEV static __device__ __forceinline__

DEV bf16 f2b(float x) { return __float2bfloat16(x); }
DEV f32x4 mfma16(bf16x8 a, bf16x8 b, f32x4 c) {
    return __builtin_amdgcn_mfma_f32_16x16x32_bf16(a, b, c, 0, 0, 0);
}
// tanh-form GELU as x*sigmoid(2u), u = 0.79788456x + 0.03567741x^3.
DEV float gelu_f(float x) {
    float u2 = x * x;
    float u = x * (0.7978845608028654f + 0.0356774081363001f * u2);
    float s = 1.f / (1.f + __expf(-2.f * u));
    return x * s;
}
// async 16B/lane global->LDS copy (LDS dest = uniform base + lane*16)
DEV void gload16(const bf16* g, bf16* l) {
    __builtin_amdgcn_global_load_lds(
        (const __attribute__((address_space(1))) unsigned int*)g,
        (__attribute__((address_space(3))) unsigned int*)l, 16, 0, 0);
}

// problem constants
constexpr int NTOK = 98;           // tokens per window (2*7*7)
constexpr int BNWIN = 1024;        // 8 * 128 windows
constexpr int MTOT = BNWIN * NTOK; // 100352
constexpr float SCALE = 0.17677669529663687f; // 32^-0.5
constexpr float EPS = 1e-5f;

// ---------------------------------------------------------------------------
// K0: one-time prep — bf16 transposed weights + attention bias table
//   QW [384][128] = qkv_w^T ; PW [128][128] = proj_w^T  (linear)
//   W1q: 16 tiles [32 hidden][128 k], k XOR-swizzled by (row&7)<<3
//   W2q: 16 tiles [128 out][32 k],    k XOR-swizzled by (col&3)<<3  (in-range!)
//   BT [4][98][98]
// ---------------------------------------------------------------------------
__global__ __launch_bounds__(256) void k_prep(const float* __restrict__ qkv_w,
        const float* __restrict__ proj_w, const float* __restrict__ fc1_w,
        const float* __restrict__ fc2_w, const float* __restrict__ rpb,
        bf16* __restrict__ QW, bf16* __restrict__ PW,
        bf16* __restrict__ W1, bf16* __restrict__ W2, float* __restrict__ BT) {
    int tid = blockIdx.x * 256 + threadIdx.x;
    int stride = gridDim.x * 256;
    for (int i = tid; i < 384 * 128; i += stride) {
        int n = i >> 7, k = i & 127;
        QW[i] = f2b(qkv_w[k * 384 + n]);
    }
    for (int i = tid; i < 128 * 128; i += stride) {
        int n = i >> 7, k = i & 127;
        PW[i] = f2b(proj_w[k * 128 + n]);
    }
    for (int i = tid; i < 512 * 128; i += stride) {   // W1q tiles
        int q = i >> 12, r = (i >> 7) & 31, kswz = i & 127;
        int k = kswz ^ ((r & 7) << 3);
        W1[i] = f2b(fc1_w[(size_t)k * 512 + q * 32 + r]);
    }
    for (int i = tid; i < 512 * 128; i += stride) {   // W2q tiles
        int q = i >> 12, c = (i >> 5) & 127, kswz = i & 31;
        int kk = kswz ^ ((c & 3) << 3);               // stays < 32
        W2[i] = f2b(fc2_w[(size_t)(q * 32 + kk) * 128 + c]);
    }
    for (int i = tid; i < 4 * 98 * 98; i += stride) {
        int h = i / 9604, r = i - h * 9604;
        int ii = r / 98, jj = r - ii * 98;
        int di = ii >= 49, ri = ii - di * 49, hi = ri / 7, wi = ri - hi * 7;
        int dj = jj >= 49, rj = jj - dj * 49, hj = rj / 7, wj = rj - hj * 7;
        int bidx = (di - dj + 1) * 169 + (hi - hj + 6) * 13 + (wi - wj + 6);
        BT[i] = rpb[bidx * 4 + h];
    }
}

// ---------------------------------------------------------------------------
// K1: LN1 + cyclic shift + window partition.  1 wave per output window-row.
// ---------------------------------------------------------------------------
__global__ __launch_bounds__(256) void k_ln1(const float* __restrict__ x,
        const float* __restrict__ g, const float* __restrict__ be,
        bf16* __restrict__ xw) {
    int wave = threadIdx.x >> 6, lane = threadIdx.x & 63;
    int r = blockIdx.x * 4 + wave;          // window row id (< 100352)
    int bn = r / 98, n = r - bn * 98;
    int b = bn >> 7, wr = bn & 127;
    int dB = wr >> 6, hB = (wr >> 3) & 7, wB = wr & 7;
    int dd = (n >= 49), rem = n - dd * 49;
    int hh = rem / 7, ww = rem - hh * 7;
    int dp = dB * 2 + dd, hp = hB * 7 + hh, wp = wB * 7 + ww;
    int ds = (dp + 1) & 3;
    int hs = hp + 3; if (hs >= 56) hs -= 56;
    int wsv = wp + 3; if (wsv >= 56) wsv -= 56;
    size_t src = ((size_t)((b * 4 + ds) * 56 + hs) * 56 + wsv) * 128;

    float2 v = *(const float2*)&x[src + lane * 2];
    float v0 = v.x, v1 = v.y;
    float s = v0 + v1, sq = v0 * v0 + v1 * v1;
    #pragma unroll
    for (int m = 1; m < 64; m <<= 1) { s += __shfl_xor(s, m); sq += __shfl_xor(sq, m); }
    float mean = s * (1.f / 128.f);
    float var = sq * (1.f / 128.f) - mean * mean;
    float rstd = rsqrtf(var + EPS);
    float g0 = g[lane * 2], g1 = g[lane * 2 + 1];
    float e0 = be[lane * 2], e1 = be[lane * 2 + 1];
    union { uint32_t u32; bf16 h[2]; } o;
    o.h[0] = f2b((v0 - mean) * rstd * g0 + e0);
    o.h[1] = f2b((v1 - mean) * rstd * g1 + e1);
    *(uint32_t*)&xw[(size_t)r * 128 + lane * 2] = o.u32;
}

// ---------------------------------------------------------------------------
// K2: QKV GEMM  (100352x128)bf16 @ QW^T + bias -> bf16   (LDS-staged B)
// ---------------------------------------------------------------------------
__global__ __launch_bounds__(256) void k_qkv(const bf16* __restrict__ A,
        const bf16* __restrict__ QW, const float* __restrict__ bias,
        bf16* __restrict__ out) {
    __shared__ __align__(16) bf16 As[64 * 136];
    __shared__ __align__(16) bf16 Bt[64 * 136];
    int tid = threadIdx.x;
    int row0 = blockIdx.x * 64;
    int col0 = blockIdx.y * 64;
    #pragma unroll
    for (int p = 0; p < 4; ++p) {
        int vi = tid + p * 256;
        int row = vi >> 4, cg = vi & 15;
        *(uint4*)&As[row * 136 + cg * 8] =
            *(const uint4*)&A[(size_t)(row0 + row) * 128 + cg * 8];
    }
    #pragma unroll
    for (int p = 0; p < 4; ++p) {
        int vi = tid + p * 256;
        int row = vi >> 4, cg = vi & 15;
        *(uint4*)&Bt[row * 136 + cg * 8] =
            *(const uint4*)&QW[(size_t)(col0 + row) * 128 + cg * 8];
    }
    __syncthreads();
    int wave = tid >> 6, lane = tid & 63;
    int wr = (wave >> 1) * 32, wc = (wave & 1) * 32;
    int lrow = lane & 15, kg8 = (lane >> 4) * 8, g4 = (lane >> 4) * 4;
    f32x4 acc[2][2] = {};
    #pragma unroll
    for (int ksi = 0; ksi < 4; ++ksi) {
        bf16x8 a[2], bb[2];
        #pragma unroll
        for (int t = 0; t < 2; ++t)
            a[t] = *(const bf16x8*)&As[(wr + t * 16 + lrow) * 136 + ksi * 32 + kg8];
        #pragma unroll
        for (int u2 = 0; u2 < 2; ++u2)
            bb[u2] = *(const bf16x8*)&Bt[(wc + u2 * 16 + lrow) * 136 + ksi * 32 + kg8];
        #pragma unroll
        for (int t = 0; t < 2; ++t)
            #pragma unroll
            for (int u2 = 0; u2 < 2; ++u2)
                acc[t][u2] = mfma16(a[t], bb[u2], acc[t][u2]);
    }
    #pragma unroll
    for (int t = 0; t < 2; ++t)
        #pragma unroll
        for (int u2 = 0; u2 < 2; ++u2) {
            int gcol = col0 + wc + u2 * 16 + lrow;
            float bv = bias[gcol];
            #pragma unroll
            for (int r2 = 0; r2 < 4; ++r2) {
                int grow = row0 + wr + t * 16 + g4 + r2;
                out[(size_t)grow * 384 + gcol] = f2b(acc[t][u2][r2] + bv);
            }
        }
}

// ---------------------------------------------------------------------------
// K3: windowed attention, one block per (window, head)
// ---------------------------------------------------------------------------
__global__ __launch_bounds__(256) void k_attn(const bf16* __restrict__ qkv,
        const float* __restrict__ BT, bf16* __restrict__ aout) {
    __shared__ __align__(16) bf16 qs[112 * 40];
    __shared__ __align__(16) bf16 ksm[112 * 40];
    __shared__ __align__(16) bf16 vt[32 * 136];
    __shared__ __align__(16) bf16 ps[64 * 136];
    __shared__ signed char trg[112];

    int tid = threadIdx.x;
    int bn = blockIdx.x, h = blockIdx.y;
    int wrw = bn & 127;
    int dB = wrw >> 6, hB = (wrw >> 3) & 7, wB = wrw & 7;

    { // zero LDS (pads matter)
        uint32_t* z1 = (uint32_t*)qs;
        uint32_t* z2 = (uint32_t*)ksm;
        for (int i = tid; i < 2240; i += 256) { z1[i] = 0u; z2[i] = 0u; }
        uint32_t* z3 = (uint32_t*)vt;
        for (int i = tid; i < 2176; i += 256) z3[i] = 0u;
        uint32_t* z4 = (uint32_t*)ps;
        for (int i = tid; i < 4352; i += 256) z4[i] = 0u;
    }
    if (tid < 112) {
        int n = tid < 98 ? tid : 97;
        int dd = n >= 49, rem = n - dd * 49;
        int hh = rem / 7, ww2 = rem - hh * 7;
        int dp = dB * 2 + dd, hp = hB * 7 + hh, wp = wB * 7 + ww2;
        int rd = dp < 2 ? 0 : (dp == 2 ? 1 : 2);
        int rh = hp < 49 ? 0 : (hp < 53 ? 1 : 2);
        int rw = wp < 49 ? 0 : (wp < 53 ? 1 : 2);
        trg[tid] = (signed char)(rd * 9 + rh * 3 + rw);
    }
    __syncthreads();
    const size_t base = (size_t)bn * 98 * 384 + h * 32;
    for (int ch = tid; ch < 1176; ch += 256) {
        int mat = ch / 392;
        int rem = ch - mat * 392;
        int row = rem >> 2, cg = rem & 3;
        uint4 v = *(const uint4*)&qkv[base + (size_t)row * 384 + mat * 128 + cg * 8];
        if (mat == 0)      *(uint4*)&qs[row * 40 + cg * 8] = v;
        else if (mat == 1) *(uint4*)&ksm[row * 40 + cg * 8] = v;
        else {
            const bf16* pv = (const bf16*)&v;
            #pragma unroll
            for (int j = 0; j < 8; ++j) vt[(cg * 8 + j) * 136 + row] = pv[j];
        }
    }
    __syncthreads();

    int wave = tid >> 6, lane = tid & 63;
    int lrow = lane & 15, kg8 = (lane >> 4) * 8, g4 = (lane >> 4) * 4;

    for (int rt = wave; rt < 7; rt += 4) {
        f32x4 sacc[7];
        bf16x8 qa = *(const bf16x8*)&qs[(rt * 16 + lrow) * 40 + kg8];
        #pragma unroll
        for (int ct = 0; ct < 7; ++ct) {
            bf16x8 kb = *(const bf16x8*)&ksm[(ct * 16 + lrow) * 40 + kg8];
            f32x4 z = {};
            sacc[ct] = mfma16(qa, kb, z);
        }
        #pragma unroll
        for (int r2 = 0; r2 < 4; ++r2) {
            int grow = rt * 16 + g4 + r2;
            int mi = grow < 98 ? grow : 97;
            int mrg = trg[mi];
            const float* btrow = &BT[((size_t)h * 98 + mi) * 98];
            float val[7];
            float mx = -1e30f;
            #pragma unroll
            for (int ct = 0; ct < 7; ++ct) {
                int jc = ct * 16 + lrow;
                int jj = jc < 98 ? jc : 97;
                float bias = btrow[jj];
                float mv = (mrg != (int)trg[jj]) ? -100.f : 0.f;
                float v = sacc[ct][r2] * SCALE + bias + mv;
                if (jc >= 98) v = -1e30f;
                val[ct] = v;
                mx = fmaxf(mx, v);
            }
            #pragma unroll
            for (int m = 1; m < 16; m <<= 1) mx = fmaxf(mx, __shfl_xor(mx, m));
            float sum = 0.f;
            #pragma unroll
            for (int ct = 0; ct < 7; ++ct) { val[ct] = __expf(val[ct] - mx); sum += val[ct]; }
            #pragma unroll
            for (int m = 1; m < 16; m <<= 1) sum += __shfl_xor(sum, m);
            float inv = 1.f / sum;
            #pragma unroll
            for (int ct = 0; ct < 7; ++ct)
                ps[(wave * 16 + g4 + r2) * 136 + ct * 16 + lrow] = f2b(val[ct] * inv);
        }
        // PV: this wave reads only the P rows it just wrote (same-wave LDS order)
        #pragma unroll
        for (int ct = 0; ct < 2; ++ct) {
            f32x4 oacc = {};
            #pragma unroll
            for (int ksi = 0; ksi < 4; ++ksi) {
                bf16x8 pa = *(const bf16x8*)&ps[(wave * 16 + lrow) * 136 + ksi * 32 + kg8];
                bf16x8 vb = *(const bf16x8*)&vt[(ct * 16 + lrow) * 136 + ksi * 32 + kg8];
                oacc = mfma16(pa, vb, oacc);
            }
            #pragma unroll
            for (int r2 = 0; r2 < 4; ++r2) {
                int grow = rt * 16 + g4 + r2;
                if (grow < 98)
                    aout[((size_t)bn * 98 + grow) * 128 + h * 32 + ct * 16 + lrow] =
                        f2b(oacc[r2]);
            }
        }
    }
}

// ---------------------------------------------------------------------------
// K4: proj GEMM + window reverse + unshift + residual + LN2  (LDS-staged B)
// ---------------------------------------------------------------------------
__global__ __launch_bounds__(256) void k_proj(const bf16* __restrict__ A,
        const bf16* __restrict__ PW, const float* __restrict__ pb,
        const float* __restrict__ x, const float* __restrict__ g2,
        const float* __restrict__ be2,
        float* __restrict__ x1, bf16* __restrict__ h2) {
    __shared__ __align__(16) bf16 As[64 * 136];
    __shared__ __align__(16) bf16 Bt[128 * 136];
    int tid = threadIdx.x;
    int row0 = blockIdx.x * 64;
    #pragma unroll
    for (int p = 0; p < 4; ++p) {
        int vi = tid + p * 256;
        int row = vi >> 4, cg = vi & 15;
        *(uint4*)&As[row * 136 + cg * 8] =
            *(const uint4*)&A[(size_t)(row0 + row) * 128 + cg * 8];
    }
    #pragma unroll
    for (int p = 0; p < 8; ++p) {
        int vi = tid + p * 256;
        int row = vi >> 4, cg = vi & 15;
        *(uint4*)&Bt[row * 136 + cg * 8] =
            *(const uint4*)&PW[(size_t)row * 128 + cg * 8];
    }
    __syncthreads();
    int wave = tid >> 6, lane = tid & 63;
    int lrow = lane & 15, kg8 = (lane >> 4) * 8, g4 = (lane >> 4) * 4;
    f32x4 acc[8] = {};
    #pragma unroll
    for (int ksi = 0; ksi < 4; ++ksi) {
        bf16x8 a = *(const bf16x8*)&As[(wave * 16 + lrow) * 136 + ksi * 32 + kg8];
        #pragma unroll
        for (int ct = 0; ct < 8; ++ct) {
            bf16x8 bb = *(const bf16x8*)&Bt[(ct * 16 + lrow) * 136 + ksi * 32 + kg8];
            acc[ct] = mfma16(a, bb, acc[ct]);
        }
    }
    #pragma unroll
    for (int r2 = 0; r2 < 4; ++r2) {
        int rwin = row0 + wave * 16 + g4 + r2;
        int bn = rwin / 98, n = rwin - bn * 98;
        int b = bn >> 7, wr2 = bn & 127;
        int dB = wr2 >> 6, hB = (wr2 >> 3) & 7, wB = wr2 & 7;
        int dd = n >= 49, rem = n - dd * 49;
        int hh = rem / 7, ww2 = rem - hh * 7;
        int dp = dB * 2 + dd, hp = hB * 7 + hh, wp = wB * 7 + ww2;
        int d2 = (dp + 1) & 3;
        int hv = hp + 3; if (hv >= 56) hv -= 56;
        int wv = wp + 3; if (wv >= 56) wv -= 56;
        size_t dst = ((size_t)(b * 4 + d2) * 56 + hv) * 56 + wv;
        float vals[8], s = 0.f, sq = 0.f;
        #pragma unroll
        for (int ct = 0; ct < 8; ++ct) {
            int col = ct * 16 + lrow;
            float v = acc[ct][r2] + pb[col] + x[dst * 128 + col];
            vals[ct] = v; s += v; sq += v * v;
        }
        #pragma unroll
        for (int m = 1; m < 16; m <<= 1) { s += __shfl_xor(s, m); sq += __shfl_xor(sq, m); }
        float mean = s * (1.f / 128.f);
        float var = sq * (1.f / 128.f) - mean * mean;
        float rstd = rsqrtf(var + EPS);
        #pragma unroll
        for (int ct = 0; ct < 8; ++ct) {
            int col = ct * 16 + lrow;
            x1[dst * 128 + col] = vals[ct];
            h2[dst * 128 + col] = f2b((vals[ct] - mean) * rstd * g2[col] + be2[col]);
        }
    }
}

// ---------------------------------------------------------------------------
// K5: fused MLP  out = x1 + gelu(h2@fc1+b1)@fc2 + b2     (out f32)
//   512 threads, 128-row tile, 16 sub-chunks of 32 hiddens.
//   LDS 26.6 KB -> 4 blocks/CU (32 waves = HW max).  A in registers.
// ---------------------------------------------------------------------------
__global__ __launch_bounds__(512) void k_mlp(const bf16* __restrict__ h2,
        const bf16* __restrict__ W1q, const float* __restrict__ b1,
        const bf16* __restrict__ W2q, const float* __restrict__ b2v,
        const float* __restrict__ x1, float* __restrict__ out) {
    __shared__ __align__(16) bf16 W1b[32 * 128];   // 8 KB, k-swizzled
    __shared__ __align__(16) bf16 W2b[128 * 32];   // 8 KB, k-swizzled
    __shared__ __align__(16) bf16 Ts[128 * 40];    // 10.2 KB
    int tid = threadIdx.x;
    int row0 = blockIdx.x * 128;
    int wave = tid >> 6, lane = tid & 63;
    int lrow = lane & 15, kg8 = (lane >> 4) * 8, g4 = (lane >> 4) * 4;
    int swz1 = (lrow & 7) << 3;    // for 128-wide W1 rows
    int swz2 = (lrow & 3) << 3;    // for 32-wide W2 rows (stays in range)

    // A fragments from global; each wave owns rows wave*16 .. wave*16+15
    bf16x8 a1[4];
    const bf16* arow = &h2[(size_t)(row0 + wave * 16 + lrow) * 128];
    #pragma unroll
    for (int ksi = 0; ksi < 4; ++ksi)
        a1[ksi] = *(const bf16x8*)&arow[ksi * 32 + kg8];

    f32x4 oacc[8] = {};
    for (int q = 0; q < 16; ++q) {
        // stage W1q(q) 8KB + W2q(q) 8KB: 16 x 1KB chunks, 8 waves x 2 issues
        const bf16* W1g = W1q + q * 4096;
        const bf16* W2g = W2q + q * 4096;
        #pragma unroll
        for (int j = 0; j < 2; ++j) {
            int chunk = wave * 2 + j;             // 0..15, wave-uniform
            if (chunk < 8) gload16(W1g + chunk * 512 + lane * 8, W1b + chunk * 512);
            else           gload16(W2g + (chunk - 8) * 512 + lane * 8, W2b + (chunk - 8) * 512);
        }
        __syncthreads();       // barrier waitcnt drains the async loads

        // fc1: 16 rows x 32 hidden per wave, K=128
        f32x4 tacc[2] = {};
        #pragma unroll
        for (int ksi = 0; ksi < 4; ++ksi) {
            int k0 = ksi * 32 + kg8;
            #pragma unroll
            for (int ct = 0; ct < 2; ++ct) {
                bf16x8 bb = *(const bf16x8*)&W1b[(ct * 16 + lrow) * 128 + (k0 ^ swz1)];
                tacc[ct] = mfma16(a1[ksi], bb, tacc[ct]);
            }
        }
        // gelu -> Ts (wave-private rows)
        #pragma unroll
        for (int ct = 0; ct < 2; ++ct) {
            float bb = b1[q * 32 + ct * 16 + lrow];
            #pragma unroll
            for (int r2 = 0; r2 < 4; ++r2) {
                float t = gelu_f(tacc[ct][r2] + bb);
                Ts[(wave * 16 + g4 + r2) * 40 + ct * 16 + lrow] = f2b(t);
            }
        }
        // fc2: 16 rows x 128 out per wave, K=32 (one MFMA K-step)
        bf16x8 a = *(const bf16x8*)&Ts[(wave * 16 + lrow) * 40 + kg8];
        #pragma unroll
        for (int ct = 0; ct < 8; ++ct) {
            bf16x8 bb = *(const bf16x8*)&W2b[(ct * 16 + lrow) * 32 + (kg8 ^ swz2)];
            oacc[ct] = mfma16(a, bb, oacc[ct]);
        }
        __syncthreads();       // all waves done reading W before next stage
    }
    #pragma unroll
    for (int ct = 0; ct < 8; ++ct) {
        int col = ct * 16 + lrow;
        float bb = b2v[col];
        #pragma unroll
        for (int r2 = 0; r2 < 4; ++r2) {
            size_t grow = (size_t)row0 + wave * 16 + g4 + r2;
            out[grow * 128 + col] = oacc[ct][r2] + bb + x1[grow * 128 + col];
        }
    }
}

// ---------------------------------------------------------------------------
extern "C" void kernel_launch(void* const* d_in, const int* in_sizes, int n_in,
                              void* d_out, int out_size, void* d_ws, size_t ws_size,
                              hipStream_t stream) {
    (void)in_sizes; (void)n_in; (void)out_size; (void)ws_size;
    const float* x      = (const float*)d_in[0];
    const float* n1g    = (const float*)d_in[1];
    const float* n1b    = (const float*)d_in[2];
    const float* qkv_w  = (const float*)d_in[3];
    const float* qkv_b  = (const float*)d_in[4];
    const float* rpb    = (const float*)d_in[5];
    const float* proj_w = (const float*)d_in[6];
    const float* proj_b = (const float*)d_in[7];
    const float* n2g    = (const float*)d_in[8];
    const float* n2b    = (const float*)d_in[9];
    const float* fc1_w  = (const float*)d_in[10];
    const float* fc1_b  = (const float*)d_in[11];
    const float* fc2_w  = (const float*)d_in[12];
    const float* fc2_b  = (const float*)d_in[13];
    float* outp = (float*)d_out;

    char* ws = (char*)d_ws;
    constexpr size_t S = (size_t)MTOT * 128 * 2;   // 25,690,112 B (one bf16 token-plane)
    bf16*  xw     = (bf16*)ws;            // [0, S)        ; reused as attn-out
    bf16*  qkvbuf = (bf16*)(ws + S);      // [S, 4S)       ; qkv (bf16)
    bf16*  aout   = xw;
    float* x1     = (float*)(ws + S);     // [S, 3S)  f32  ; reuse after attention
    bf16*  h2     = (bf16*)(ws + 3 * S);  // [3S, 4S)
    // weight area after 4S
    char* wp_ = ws + 4 * S;
    bf16*  QW  = (bf16*)wp_;                      // 384*128*2 = 98304
    bf16*  PW  = (bf16*)(wp_ + 98304);            // 128*128*2 = 32768
    bf16*  W1q = (bf16*)(wp_ + 98304 + 32768);    // 512*128*2 = 131072 (16 tiles)
    bf16*  W2q = (bf16*)(wp_ + 98304 + 32768 + 131072);  // 131072 (16 tiles)
    float* BTb = (float*)(wp_ + 98304 + 32768 + 131072 + 131072); // 4*98*98*4

    k_prep<<<192, 256, 0, stream>>>(qkv_w, proj_w, fc1_w, fc2_w, rpb, QW, PW, W1q, W2q, BTb);
    k_ln1 <<<MTOT / 4, 256, 0, stream>>>(x, n1g, n1b, xw);
    k_qkv <<<dim3(MTOT / 64, 6), 256, 0, stream>>>(xw, QW, qkv_b, qkvbuf);
    k_attn<<<dim3(BNWIN, 4), 256, 0, stream>>>(qkvbuf, BTb, aout);
    k_proj<<<MTOT / 64, 256, 0, stream>>>(aout, PW, proj_b, x, n2g, n2b, x1, h2);
    k_mlp <<<MTOT / 128, 512, 0, stream>>>(h2, W1q, fc1_b, W2q, fc2_b, x1, outp);
}

// Round 10
// 219.261 us; speedup vs baseline: 1.0301x; 1.0301x over previous
//
#include <hip/hip_runtime.h>
#include <hip/hip_bf16.h>
#include <cstdint>
#include <cstddef>

using bf16 = __hip_bfloat16;
typedef __bf16 bf16x8 __attribute__((ext_vector_type(8)));
typedef float f32x4 __attribute__((ext_vector_type(4)));

#define DEV static __device__ __forceinline__

DEV bf16 f2b(float x) { return __float2bfloat16(x); }
DEV f32x4 mfma16(bf16x8 a, bf16x8 b, f32x4 c) {
    return __builtin_amdgcn_mfma_f32_16x16x32_bf16(a, b, c, 0, 0, 0);
}
// tanh-form GELU as x*sigmoid(2u), u = 0.79788456x + 0.03567741x^3.
DEV float gelu_f(float x) {
    float u2 = x * x;
    float u = x * (0.7978845608028654f + 0.0356774081363001f * u2);
    float s = 1.f / (1.f + __expf(-2.f * u));
    return x * s;
}
// async 16B/lane global->LDS copy (LDS dest = uniform base + lane*16)
DEV void gload16(const bf16* g, bf16* l) {
    __builtin_amdgcn_global_load_lds(
        (const __attribute__((address_space(1))) unsigned int*)g,
        (__attribute__((address_space(3))) unsigned int*)l, 16, 0, 0);
}

// problem constants
constexpr int NTOK = 98;           // tokens per window (2*7*7)
constexpr int BNWIN = 1024;        // 8 * 128 windows
constexpr int MTOT = BNWIN * NTOK; // 100352
constexpr float SCALE = 0.17677669529663687f; // 32^-0.5
constexpr float EPS = 1e-5f;

// ---------------------------------------------------------------------------
// K0: one-time prep — bf16 transposed weights + attention bias table
//   QW [384][128] = qkv_w^T ; PW [128][128] = proj_w^T  (linear)
//   W1s: 8 tiles [64 hidden][128 k], k XOR-swizzled by (row&7)<<3
//   W2s: 8 tiles [128 out][64 k],    k XOR-swizzled by (col&7)<<3
//   BT [4][98][98]
// ---------------------------------------------------------------------------
__global__ __launch_bounds__(256) void k_prep(const float* __restrict__ qkv_w,
        const float* __restrict__ proj_w, const float* __restrict__ fc1_w,
        const float* __restrict__ fc2_w, const float* __restrict__ rpb,
        bf16* __restrict__ QW, bf16* __restrict__ PW,
        bf16* __restrict__ W1, bf16* __restrict__ W2, float* __restrict__ BT) {
    int tid = blockIdx.x * 256 + threadIdx.x;
    int stride = gridDim.x * 256;
    for (int i = tid; i < 384 * 128; i += stride) {
        int n = i >> 7, k = i & 127;
        QW[i] = f2b(qkv_w[k * 384 + n]);
    }
    for (int i = tid; i < 128 * 128; i += stride) {
        int n = i >> 7, k = i & 127;
        PW[i] = f2b(proj_w[k * 128 + n]);
    }
    for (int i = tid; i < 512 * 128; i += stride) {   // W1s swizzled
        int t = i >> 13, r = (i >> 7) & 63, kswz = i & 127;
        int k = kswz ^ ((r & 7) << 3);
        W1[i] = f2b(fc1_w[(size_t)k * 512 + t * 64 + r]);
    }
    for (int i = tid; i < 512 * 128; i += stride) {   // W2s swizzled
        int t = i >> 13, c = (i >> 6) & 127, kswz = i & 63;
        int kk = kswz ^ ((c & 7) << 3);               // < 64, in range
        W2[i] = f2b(fc2_w[(size_t)(t * 64 + kk) * 128 + c]);
    }
    for (int i = tid; i < 4 * 98 * 98; i += stride) {
        int h = i / 9604, r = i - h * 9604;
        int ii = r / 98, jj = r - ii * 98;
        int di = ii >= 49, ri = ii - di * 49, hi = ri / 7, wi = ri - hi * 7;
        int dj = jj >= 49, rj = jj - dj * 49, hj = rj / 7, wj = rj - hj * 7;
        int bidx = (di - dj + 1) * 169 + (hi - hj + 6) * 13 + (wi - wj + 6);
        BT[i] = rpb[bidx * 4 + h];
    }
}

// ---------------------------------------------------------------------------
// K1: LN1 + cyclic shift + window partition.  1 wave per output window-row.
// ---------------------------------------------------------------------------
__global__ __launch_bounds__(256) void k_ln1(const float* __restrict__ x,
        const float* __restrict__ g, const float* __restrict__ be,
        bf16* __restrict__ xw) {
    int wave = threadIdx.x >> 6, lane = threadIdx.x & 63;
    int r = blockIdx.x * 4 + wave;          // window row id (< 100352)
    int bn = r / 98, n = r - bn * 98;
    int b = bn >> 7, wr = bn & 127;
    int dB = wr >> 6, hB = (wr >> 3) & 7, wB = wr & 7;
    int dd = (n >= 49), rem = n - dd * 49;
    int hh = rem / 7, ww = rem - hh * 7;
    int dp = dB * 2 + dd, hp = hB * 7 + hh, wp = wB * 7 + ww;
    int ds = (dp + 1) & 3;
    int hs = hp + 3; if (hs >= 56) hs -= 56;
    int wsv = wp + 3; if (wsv >= 56) wsv -= 56;
    size_t src = ((size_t)((b * 4 + ds) * 56 + hs) * 56 + wsv) * 128;

    float2 v = *(const float2*)&x[src + lane * 2];
    float v0 = v.x, v1 = v.y;
    float s = v0 + v1, sq = v0 * v0 + v1 * v1;
    #pragma unroll
    for (int m = 1; m < 64; m <<= 1) { s += __shfl_xor(s, m); sq += __shfl_xor(sq, m); }
    float mean = s * (1.f / 128.f);
    float var = sq * (1.f / 128.f) - mean * mean;
    float rstd = rsqrtf(var + EPS);
    float g0 = g[lane * 2], g1 = g[lane * 2 + 1];
    float e0 = be[lane * 2], e1 = be[lane * 2 + 1];
    union { uint32_t u32; bf16 h[2]; } o;
    o.h[0] = f2b((v0 - mean) * rstd * g0 + e0);
    o.h[1] = f2b((v1 - mean) * rstd * g1 + e1);
    *(uint32_t*)&xw[(size_t)r * 128 + lane * 2] = o.u32;
}

// ---------------------------------------------------------------------------
// K2: QKV GEMM  (100352x128)bf16 @ QW^T + bias -> bf16   (LDS-staged B)
// ---------------------------------------------------------------------------
__global__ __launch_bounds__(256) void k_qkv(const bf16* __restrict__ A,
        const bf16* __restrict__ QW, const float* __restrict__ bias,
        bf16* __restrict__ out) {
    __shared__ __align__(16) bf16 As[64 * 136];
    __shared__ __align__(16) bf16 Bt[64 * 136];
    int tid = threadIdx.x;
    int row0 = blockIdx.x * 64;
    int col0 = blockIdx.y * 64;
    #pragma unroll
    for (int p = 0; p < 4; ++p) {
        int vi = tid + p * 256;
        int row = vi >> 4, cg = vi & 15;
        *(uint4*)&As[row * 136 + cg * 8] =
            *(const uint4*)&A[(size_t)(row0 + row) * 128 + cg * 8];
    }
    #pragma unroll
    for (int p = 0; p < 4; ++p) {
        int vi = tid + p * 256;
        int row = vi >> 4, cg = vi & 15;
        *(uint4*)&Bt[row * 136 + cg * 8] =
            *(const uint4*)&QW[(size_t)(col0 + row) * 128 + cg * 8];
    }
    __syncthreads();
    int wave = tid >> 6, lane = tid & 63;
    int wr = (wave >> 1) * 32, wc = (wave & 1) * 32;
    int lrow = lane & 15, kg8 = (lane >> 4) * 8, g4 = (lane >> 4) * 4;
    f32x4 acc[2][2] = {};
    #pragma unroll
    for (int ksi = 0; ksi < 4; ++ksi) {
        bf16x8 a[2], bb[2];
        #pragma unroll
        for (int t = 0; t < 2; ++t)
            a[t] = *(const bf16x8*)&As[(wr + t * 16 + lrow) * 136 + ksi * 32 + kg8];
        #pragma unroll
        for (int u2 = 0; u2 < 2; ++u2)
            bb[u2] = *(const bf16x8*)&Bt[(wc + u2 * 16 + lrow) * 136 + ksi * 32 + kg8];
        #pragma unroll
        for (int t = 0; t < 2; ++t)
            #pragma unroll
            for (int u2 = 0; u2 < 2; ++u2)
                acc[t][u2] = mfma16(a[t], bb[u2], acc[t][u2]);
    }
    #pragma unroll
    for (int t = 0; t < 2; ++t)
        #pragma unroll
        for (int u2 = 0; u2 < 2; ++u2) {
            int gcol = col0 + wc + u2 * 16 + lrow;
            float bv = bias[gcol];
            #pragma unroll
            for (int r2 = 0; r2 < 4; ++r2) {
                int grow = row0 + wr + t * 16 + g4 + r2;
                out[(size_t)grow * 384 + gcol] = f2b(acc[t][u2][r2] + bv);
            }
        }
}

// ---------------------------------------------------------------------------
// K3: windowed attention, one block per (window, head)
// ---------------------------------------------------------------------------
__global__ __launch_bounds__(256) void k_attn(const bf16* __restrict__ qkv,
        const float* __restrict__ BT, bf16* __restrict__ aout) {
    __shared__ __align__(16) bf16 qs[112 * 40];
    __shared__ __align__(16) bf16 ksm[112 * 40];
    __shared__ __align__(16) bf16 vt[32 * 136];
    __shared__ __align__(16) bf16 ps[64 * 136];
    __shared__ signed char trg[112];

    int tid = threadIdx.x;
    int bn = blockIdx.x, h = blockIdx.y;
    int wrw = bn & 127;
    int dB = wrw >> 6, hB = (wrw >> 3) & 7, wB = wrw & 7;

    { // zero LDS (pads matter)
        uint32_t* z1 = (uint32_t*)qs;
        uint32_t* z2 = (uint32_t*)ksm;
        for (int i = tid; i < 2240; i += 256) { z1[i] = 0u; z2[i] = 0u; }
        uint32_t* z3 = (uint32_t*)vt;
        for (int i = tid; i < 2176; i += 256) z3[i] = 0u;
        uint32_t* z4 = (uint32_t*)ps;
        for (int i = tid; i < 4352; i += 256) z4[i] = 0u;
    }
    if (tid < 112) {
        int n = tid < 98 ? tid : 97;
        int dd = n >= 49, rem = n - dd * 49;
        int hh = rem / 7, ww2 = rem - hh * 7;
        int dp = dB * 2 + dd, hp = hB * 7 + hh, wp = wB * 7 + ww2;
        int rd = dp < 2 ? 0 : (dp == 2 ? 1 : 2);
        int rh = hp < 49 ? 0 : (hp < 53 ? 1 : 2);
        int rw = wp < 49 ? 0 : (wp < 53 ? 1 : 2);
        trg[tid] = (signed char)(rd * 9 + rh * 3 + rw);
    }
    __syncthreads();
    const size_t base = (size_t)bn * 98 * 384 + h * 32;
    for (int ch = tid; ch < 1176; ch += 256) {
        int mat = ch / 392;
        int rem = ch - mat * 392;
        int row = rem >> 2, cg = rem & 3;
        uint4 v = *(const uint4*)&qkv[base + (size_t)row * 384 + mat * 128 + cg * 8];
        if (mat == 0)      *(uint4*)&qs[row * 40 + cg * 8] = v;
        else if (mat == 1) *(uint4*)&ksm[row * 40 + cg * 8] = v;
        else {
            const bf16* pv = (const bf16*)&v;
            #pragma unroll
            for (int j = 0; j < 8; ++j) vt[(cg * 8 + j) * 136 + row] = pv[j];
        }
    }
    __syncthreads();

    int wave = tid >> 6, lane = tid & 63;
    int lrow = lane & 15, kg8 = (lane >> 4) * 8, g4 = (lane >> 4) * 4;

    for (int rt = wave; rt < 7; rt += 4) {
        f32x4 sacc[7];
        bf16x8 qa = *(const bf16x8*)&qs[(rt * 16 + lrow) * 40 + kg8];
        #pragma unroll
        for (int ct = 0; ct < 7; ++ct) {
            bf16x8 kb = *(const bf16x8*)&ksm[(ct * 16 + lrow) * 40 + kg8];
            f32x4 z = {};
            sacc[ct] = mfma16(qa, kb, z);
        }
        #pragma unroll
        for (int r2 = 0; r2 < 4; ++r2) {
            int grow = rt * 16 + g4 + r2;
            int mi = grow < 98 ? grow : 97;
            int mrg = trg[mi];
            const float* btrow = &BT[((size_t)h * 98 + mi) * 98];
            float val[7];
            float mx = -1e30f;
            #pragma unroll
            for (int ct = 0; ct < 7; ++ct) {
                int jc = ct * 16 + lrow;
                int jj = jc < 98 ? jc : 97;
                float bias = btrow[jj];
                float mv = (mrg != (int)trg[jj]) ? -100.f : 0.f;
                float v = sacc[ct][r2] * SCALE + bias + mv;
                if (jc >= 98) v = -1e30f;
                val[ct] = v;
                mx = fmaxf(mx, v);
            }
            #pragma unroll
            for (int m = 1; m < 16; m <<= 1) mx = fmaxf(mx, __shfl_xor(mx, m));
            float sum = 0.f;
            #pragma unroll
            for (int ct = 0; ct < 7; ++ct) { val[ct] = __expf(val[ct] - mx); sum += val[ct]; }
            #pragma unroll
            for (int m = 1; m < 16; m <<= 1) sum += __shfl_xor(sum, m);
            float inv = 1.f / sum;
            #pragma unroll
            for (int ct = 0; ct < 7; ++ct)
                ps[(wave * 16 + g4 + r2) * 136 + ct * 16 + lrow] = f2b(val[ct] * inv);
        }
        // PV: this wave reads only the P rows it just wrote (same-wave LDS order)
        #pragma unroll
        for (int ct = 0; ct < 2; ++ct) {
            f32x4 oacc = {};
            #pragma unroll
            for (int ksi = 0; ksi < 4; ++ksi) {
                bf16x8 pa = *(const bf16x8*)&ps[(wave * 16 + lrow) * 136 + ksi * 32 + kg8];
                bf16x8 vb = *(const bf16x8*)&vt[(ct * 16 + lrow) * 136 + ksi * 32 + kg8];
                oacc = mfma16(pa, vb, oacc);
            }
            #pragma unroll
            for (int r2 = 0; r2 < 4; ++r2) {
                int grow = rt * 16 + g4 + r2;
                if (grow < 98)
                    aout[((size_t)bn * 98 + grow) * 128 + h * 32 + ct * 16 + lrow] =
                        f2b(oacc[r2]);
            }
        }
    }
}

// ---------------------------------------------------------------------------
// K4: proj GEMM + window reverse + unshift + residual + LN2  (LDS-staged B)
// ---------------------------------------------------------------------------
__global__ __launch_bounds__(256) void k_proj(const bf16* __restrict__ A,
        const bf16* __restrict__ PW, const float* __restrict__ pb,
        const float* __restrict__ x, const float* __restrict__ g2,
        const float* __restrict__ be2,
        float* __restrict__ x1, bf16* __restrict__ h2) {
    __shared__ __align__(16) bf16 As[64 * 136];
    __shared__ __align__(16) bf16 Bt[128 * 136];
    int tid = threadIdx.x;
    int row0 = blockIdx.x * 64;
    #pragma unroll
    for (int p = 0; p < 4; ++p) {
        int vi = tid + p * 256;
        int row = vi >> 4, cg = vi & 15;
        *(uint4*)&As[row * 136 + cg * 8] =
            *(const uint4*)&A[(size_t)(row0 + row) * 128 + cg * 8];
    }
    #pragma unroll
    for (int p = 0; p < 8; ++p) {
        int vi = tid + p * 256;
        int row = vi >> 4, cg = vi & 15;
        *(uint4*)&Bt[row * 136 + cg * 8] =
            *(const uint4*)&PW[(size_t)row * 128 + cg * 8];
    }
    __syncthreads();
    int wave = tid >> 6, lane = tid & 63;
    int lrow = lane & 15, kg8 = (lane >> 4) * 8, g4 = (lane >> 4) * 4;
    f32x4 acc[8] = {};
    #pragma unroll
    for (int ksi = 0; ksi < 4; ++ksi) {
        bf16x8 a = *(const bf16x8*)&As[(wave * 16 + lrow) * 136 + ksi * 32 + kg8];
        #pragma unroll
        for (int ct = 0; ct < 8; ++ct) {
            bf16x8 bb = *(const bf16x8*)&Bt[(ct * 16 + lrow) * 136 + ksi * 32 + kg8];
            acc[ct] = mfma16(a, bb, acc[ct]);
        }
    }
    #pragma unroll
    for (int r2 = 0; r2 < 4; ++r2) {
        int rwin = row0 + wave * 16 + g4 + r2;
        int bn = rwin / 98, n = rwin - bn * 98;
        int b = bn >> 7, wr2 = bn & 127;
        int dB = wr2 >> 6, hB = (wr2 >> 3) & 7, wB = wr2 & 7;
        int dd = n >= 49, rem = n - dd * 49;
        int hh = rem / 7, ww2 = rem - hh * 7;
        int dp = dB * 2 + dd, hp = hB * 7 + hh, wp = wB * 7 + ww2;
        int d2 = (dp + 1) & 3;
        int hv = hp + 3; if (hv >= 56) hv -= 56;
        int wv = wp + 3; if (wv >= 56) wv -= 56;
        size_t dst = ((size_t)(b * 4 + d2) * 56 + hv) * 56 + wv;
        float vals[8], s = 0.f, sq = 0.f;
        #pragma unroll
        for (int ct = 0; ct < 8; ++ct) {
            int col = ct * 16 + lrow;
            float v = acc[ct][r2] + pb[col] + x[dst * 128 + col];
            vals[ct] = v; s += v; sq += v * v;
        }
        #pragma unroll
        for (int m = 1; m < 16; m <<= 1) { s += __shfl_xor(s, m); sq += __shfl_xor(sq, m); }
        float mean = s * (1.f / 128.f);
        float var = sq * (1.f / 128.f) - mean * mean;
        float rstd = rsqrtf(var + EPS);
        #pragma unroll
        for (int ct = 0; ct < 8; ++ct) {
            int col = ct * 16 + lrow;
            x1[dst * 128 + col] = vals[ct];
            h2[dst * 128 + col] = f2b((vals[ct] - mean) * rstd * g2[col] + be2[col]);
        }
    }
}

// ---------------------------------------------------------------------------
// K5: fused MLP  out = x1 + gelu(h2@fc1+b1)@fc2 + b2     (out f32)
//   256 threads / 4 waves; each wave owns 32 rows (2 A-frags) -> every
//   B-fragment LDS read feeds 2 MFMAs (halves LDS ops per FLOP).
//   8 phases of 64 hiddens; async global_load_lds staging; 50.6 KB LDS.
// ---------------------------------------------------------------------------
__global__ __launch_bounds__(256) void k_mlp(const bf16* __restrict__ h2,
        const bf16* __restrict__ W1s, const float* __restrict__ b1,
        const bf16* __restrict__ W2s, const float* __restrict__ b2v,
        const float* __restrict__ x1, float* __restrict__ out) {
    __shared__ __align__(16) bf16 W1b[64 * 128];   // 16 KB, k-swizzled
    __shared__ __align__(16) bf16 W2b[128 * 64];   // 16 KB, k-swizzled
    __shared__ __align__(16) bf16 Ts[128 * 72];    // 18.4 KB
    int tid = threadIdx.x;
    int row0 = blockIdx.x * 128;
    int wave = tid >> 6, lane = tid & 63;
    int lrow = lane & 15, kg8 = (lane >> 4) * 8, g4 = (lane >> 4) * 4;
    int swz = (lrow & 7) << 3;

    // A fragments from global; wave owns rows wave*32 .. wave*32+31 (2 frags)
    bf16x8 a1[2][4];
    #pragma unroll
    for (int r = 0; r < 2; ++r) {
        const bf16* arow = &h2[(size_t)(row0 + wave * 32 + r * 16 + lrow) * 128];
        #pragma unroll
        for (int ksi = 0; ksi < 4; ++ksi)
            a1[r][ksi] = *(const bf16x8*)&arow[ksi * 32 + kg8];
    }

    f32x4 oacc[2][8] = {};
    for (int q = 0; q < 8; ++q) {
        // stage W1s(q) 16KB + W2s(q) 16KB: 32 x 1KB chunks, 4 waves x 8 issues
        const bf16* W1g = W1s + q * 8192;
        const bf16* W2g = W2s + q * 8192;
        #pragma unroll
        for (int j = 0; j < 8; ++j) {
            int chunk = wave * 8 + j;             // 0..31, wave-uniform
            if (chunk < 16) gload16(W1g + chunk * 512 + lane * 8, W1b + chunk * 512);
            else            gload16(W2g + (chunk - 16) * 512 + lane * 8, W2b + (chunk - 16) * 512);
        }
        __syncthreads();       // barrier waitcnt drains the async loads

        // fc1: 32 rows x 64 hidden per wave, K=128 (each B-read feeds 2 MFMAs)
        f32x4 tacc[2][4] = {};
        #pragma unroll
        for (int ksi = 0; ksi < 4; ++ksi) {
            int k0 = ksi * 32 + kg8;
            #pragma unroll
            for (int h = 0; h < 4; ++h) {
                bf16x8 bb = *(const bf16x8*)&W1b[(h * 16 + lrow) * 128 + (k0 ^ swz)];
                #pragma unroll
                for (int r = 0; r < 2; ++r)
                    tacc[r][h] = mfma16(a1[r][ksi], bb, tacc[r][h]);
            }
        }
        // gelu -> Ts (wave-private rows)
        #pragma unroll
        for (int h = 0; h < 4; ++h) {
            float bb = b1[q * 64 + h * 16 + lrow];
            #pragma unroll
            for (int r = 0; r < 2; ++r)
                #pragma unroll
                for (int r2 = 0; r2 < 4; ++r2) {
                    float t = gelu_f(tacc[r][h][r2] + bb);
                    Ts[(wave * 32 + r * 16 + g4 + r2) * 72 + h * 16 + lrow] = f2b(t);
                }
        }
        // fc2: 32 rows x 128 out per wave, K=64 (each B-read feeds 2 MFMAs)
        #pragma unroll
        for (int ksi = 0; ksi < 2; ++ksi) {
            int k0 = ksi * 32 + kg8;
            bf16x8 a[2];
            #pragma unroll
            for (int r = 0; r < 2; ++r)
                a[r] = *(const bf16x8*)&Ts[(wave * 32 + r * 16 + lrow) * 72 + k0];
            #pragma unroll
            for (int ct = 0; ct < 8; ++ct) {
                bf16x8 bb = *(const bf16x8*)&W2b[(ct * 16 + lrow) * 64 + (k0 ^ swz)];
                #pragma unroll
                for (int r = 0; r < 2; ++r)
                    oacc[r][ct] = mfma16(a[r], bb, oacc[r][ct]);
            }
        }
        __syncthreads();       // all waves done reading W before next stage
    }
    #pragma unroll
    for (int ct = 0; ct < 8; ++ct) {
        int col = ct * 16 + lrow;
        float bb = b2v[col];
        #pragma unroll
        for (int r = 0; r < 2; ++r)
            #pragma unroll
            for (int r2 = 0; r2 < 4; ++r2) {
                size_t grow = (size_t)row0 + wave * 32 + r * 16 + g4 + r2;
                out[grow * 128 + col] = oacc[r][ct][r2] + bb + x1[grow * 128 + col];
            }
    }
}

// ---------------------------------------------------------------------------
extern "C" void kernel_launch(void* const* d_in, const int* in_sizes, int n_in,
                              void* d_out, int out_size, void* d_ws, size_t ws_size,
                              hipStream_t stream) {
    (void)in_sizes; (void)n_in; (void)out_size; (void)ws_size;
    const float* x      = (const float*)d_in[0];
    const float* n1g    = (const float*)d_in[1];
    const float* n1b    = (const float*)d_in[2];
    const float* qkv_w  = (const float*)d_in[3];
    const float* qkv_b  = (const float*)d_in[4];
    const float* rpb    = (const float*)d_in[5];
    const float* proj_w = (const float*)d_in[6];
    const float* proj_b = (const float*)d_in[7];
    const float* n2g    = (const float*)d_in[8];
    const float* n2b    = (const float*)d_in[9];
    const float* fc1_w  = (const float*)d_in[10];
    const float* fc1_b  = (const float*)d_in[11];
    const float* fc2_w  = (const float*)d_in[12];
    const float* fc2_b  = (const float*)d_in[13];
    float* outp = (float*)d_out;

    char* ws = (char*)d_ws;
    constexpr size_t S = (size_t)MTOT * 128 * 2;   // 25,690,112 B (one bf16 token-plane)
    bf16*  xw     = (bf16*)ws;            // [0, S)        ; reused as attn-out
    bf16*  qkvbuf = (bf16*)(ws + S);      // [S, 4S)       ; qkv (bf16)
    bf16*  aout   = xw;
    float* x1     = (float*)(ws + S);     // [S, 3S)  f32  ; reuse after attention
    bf16*  h2     = (bf16*)(ws + 3 * S);  // [3S, 4S)
    // weight area after 4S
    char* wp_ = ws + 4 * S;
    bf16*  QW  = (bf16*)wp_;                      // 384*128*2 = 98304
    bf16*  PW  = (bf16*)(wp_ + 98304);            // 128*128*2 = 32768
    bf16*  W1s = (bf16*)(wp_ + 98304 + 32768);    // 512*128*2 = 131072 (8 tiles)
    bf16*  W2s = (bf16*)(wp_ + 98304 + 32768 + 131072);  // 131072 (8 tiles)
    float* BTb = (float*)(wp_ + 98304 + 32768 + 131072 + 131072); // 4*98*98*4

    k_prep<<<192, 256, 0, stream>>>(qkv_w, proj_w, fc1_w, fc2_w, rpb, QW, PW, W1s, W2s, BTb);
    k_ln1 <<<MTOT / 4, 256, 0, stream>>>(x, n1g, n1b, xw);
    k_qkv <<<dim3(MTOT / 64, 6), 256, 0, stream>>>(xw, QW, qkv_b, qkvbuf);
    k_attn<<<dim3(BNWIN, 4), 256, 0, stream>>>(qkvbuf, BTb, aout);
    k_proj<<<MTOT / 64, 256, 0, stream>>>(aout, PW, proj_b, x, n2g, n2b, x1, h2);
    k_mlp <<<MTOT / 128, 256, 0, stream>>>(h2, W1s, fc1_b, W2s, fc2_b, x1, outp);
}

// Round 12
// 197.864 us; speedup vs baseline: 1.1415x; 1.1081x over previous
//
#include <hip/hip_runtime.h>
#include <hip/hip_bf16.h>
#include <cstdint>
#include <cstddef>

using bf16 = __hip_bfloat16;
typedef __bf16 bf16x8 __attribute__((ext_vector_type(8)));
typedef float f32x4 __attribute__((ext_vector_type(4)));

#define DEV static __device__ __forceinline__

DEV bf16 f2b(float x) { return __float2bfloat16(x); }
DEV float b2f(bf16 x) { return __bfloat162float(x); }
DEV f32x4 mfma16(bf16x8 a, bf16x8 b, f32x4 c) {
    return __builtin_amdgcn_mfma_f32_16x16x32_bf16(a, b, c, 0, 0, 0);
}
// tanh-form GELU as x*sigmoid(2u), u = 0.79788456x + 0.03567741x^3.
DEV float gelu_f(float x) {
    float u2 = x * x;
    float u = x * (0.7978845608028654f + 0.0356774081363001f * u2);
    float s = 1.f / (1.f + __expf(-2.f * u));
    return x * s;
}
// async 16B/lane global->LDS copy (LDS dest = uniform base + lane*16)
DEV void gload16(const bf16* g, bf16* l) {
    __builtin_amdgcn_global_load_lds(
        (const __attribute__((address_space(1))) unsigned int*)g,
        (__attribute__((address_space(3))) unsigned int*)l, 16, 0, 0);
}

// problem constants
constexpr int NTOK = 98;           // tokens per window (2*7*7)
constexpr int BNWIN = 1024;        // 8 * 128 windows
constexpr int MTOT = BNWIN * NTOK; // 100352
constexpr float SCALE = 0.17677669529663687f; // 32^-0.5
constexpr float EPS = 1e-5f;

// ---------------------------------------------------------------------------
// K0: one-time prep — bf16 transposed + swizzled weights + bias table
//   QWs: 6 tiles [64 n][128 k],  k ^= (n&7)<<3
//   PW  [128][128] = proj_w^T (linear)
//   W1s: 8 tiles [64 hid][128 k], k ^= (r&7)<<3
//   W2s: 8 tiles [128 out][64 k], k ^= (c&7)<<3
//   BT [4][98][98]
// ---------------------------------------------------------------------------
__global__ __launch_bounds__(256) void k_prep(const float* __restrict__ qkv_w,
        const float* __restrict__ proj_w, const float* __restrict__ fc1_w,
        const float* __restrict__ fc2_w, const float* __restrict__ rpb,
        bf16* __restrict__ QWs, bf16* __restrict__ PW,
        bf16* __restrict__ W1, bf16* __restrict__ W2, float* __restrict__ BT) {
    int tid = blockIdx.x * 256 + threadIdx.x;
    int stride = gridDim.x * 256;
    for (int i = tid; i < 384 * 128; i += stride) {   // QWs tiles
        int t = i >> 13, r = (i >> 7) & 63, kswz = i & 127;
        int k = kswz ^ ((r & 7) << 3);
        QWs[i] = f2b(qkv_w[(size_t)k * 384 + t * 64 + r]);
    }
    for (int i = tid; i < 128 * 128; i += stride) {
        int n = i >> 7, k = i & 127;
        PW[i] = f2b(proj_w[k * 128 + n]);
    }
    for (int i = tid; i < 512 * 128; i += stride) {   // W1s tiles
        int t = i >> 13, r = (i >> 7) & 63, kswz = i & 127;
        int k = kswz ^ ((r & 7) << 3);
        W1[i] = f2b(fc1_w[(size_t)k * 512 + t * 64 + r]);
    }
    for (int i = tid; i < 512 * 128; i += stride) {   // W2s tiles
        int t = i >> 13, c = (i >> 6) & 127, kswz = i & 63;
        int kk = kswz ^ ((c & 7) << 3);               // < 64, in range
        W2[i] = f2b(fc2_w[(size_t)(t * 64 + kk) * 128 + c]);
    }
    for (int i = tid; i < 4 * 98 * 98; i += stride) {
        int h = i / 9604, r = i - h * 9604;
        int ii = r / 98, jj = r - ii * 98;
        int di = ii >= 49, ri = ii - di * 49, hi = ri / 7, wi = ri - hi * 7;
        int dj = jj >= 49, rj = jj - dj * 49, hj = rj / 7, wj = rj - hj * 7;
        int bidx = (di - dj + 1) * 169 + (hi - hj + 6) * 13 + (wi - wj + 6);
        BT[i] = rpb[bidx * 4 + h];
    }
}

// ---------------------------------------------------------------------------
// K2: fused LN1 + shift + window-partition + QKV GEMM
//   Single Bt buffer; stage -> barrier -> compute -> barrier per col phase
//   (replay-proven topology).  LDS 33.8 KB -> 4 blocks/CU.
// ---------------------------------------------------------------------------
__global__ __launch_bounds__(256) void k_qkvln(const float* __restrict__ x,
        const float* __restrict__ g, const float* __restrict__ be,
        const bf16* __restrict__ QWs, const float* __restrict__ bias,
        bf16* __restrict__ out) {
    __shared__ __align__(16) bf16 As[64 * 136];
    __shared__ __align__(16) bf16 Bt[64 * 128];
    int tid = threadIdx.x;
    int row0 = blockIdx.x * 64;
    int wave = tid >> 6, lane = tid & 63;
    int lrow = lane & 15, kg8 = (lane >> 4) * 8, g4 = (lane >> 4) * 4;
    int swzq = (lrow & 7) << 3;

    // ---- LN1 + gather staging: 4 phases, 16 threads per row ----
    #pragma unroll
    for (int p = 0; p < 4; ++p) {
        int vi = tid + p * 256;
        int row = vi >> 4, cg = vi & 15;
        int r = row0 + row;
        int bn = r / 98, n = r - bn * 98;
        int b = bn >> 7, wr = bn & 127;
        int dB = wr >> 6, hB = (wr >> 3) & 7, wB = wr & 7;
        int dd = (n >= 49), rem = n - dd * 49;
        int hh = rem / 7, ww = rem - hh * 7;
        int dp = dB * 2 + dd, hp = hB * 7 + hh, wp = wB * 7 + ww;
        int ds = (dp + 1) & 3;
        int hs = hp + 3; if (hs >= 56) hs -= 56;
        int wsv = wp + 3; if (wsv >= 56) wsv -= 56;
        size_t src = ((size_t)((b * 4 + ds) * 56 + hs) * 56 + wsv) * 128 + cg * 8;
        float4 v0 = *(const float4*)&x[src];
        float4 v1 = *(const float4*)&x[src + 4];
        float s = v0.x + v0.y + v0.z + v0.w + v1.x + v1.y + v1.z + v1.w;
        float sq = v0.x*v0.x + v0.y*v0.y + v0.z*v0.z + v0.w*v0.w
                 + v1.x*v1.x + v1.y*v1.y + v1.z*v1.z + v1.w*v1.w;
        #pragma unroll
        for (int m = 1; m < 16; m <<= 1) { s += __shfl_xor(s, m); sq += __shfl_xor(sq, m); }
        float mean = s * (1.f / 128.f);
        float var = sq * (1.f / 128.f) - mean * mean;
        float rstd = rsqrtf(var + EPS);
        float4 g0 = *(const float4*)&g[cg * 8], g1 = *(const float4*)&g[cg * 8 + 4];
        float4 e0 = *(const float4*)&be[cg * 8], e1 = *(const float4*)&be[cg * 8 + 4];
        union { bf16x8 v8; bf16 h[8]; } o;
        o.h[0] = f2b((v0.x - mean) * rstd * g0.x + e0.x);
        o.h[1] = f2b((v0.y - mean) * rstd * g0.y + e0.y);
        o.h[2] = f2b((v0.z - mean) * rstd * g0.z + e0.z);
        o.h[3] = f2b((v0.w - mean) * rstd * g0.w + e0.w);
        o.h[4] = f2b((v1.x - mean) * rstd * g1.x + e1.x);
        o.h[5] = f2b((v1.y - mean) * rstd * g1.y + e1.y);
        o.h[6] = f2b((v1.z - mean) * rstd * g1.z + e1.z);
        o.h[7] = f2b((v1.w - mean) * rstd * g1.w + e1.w);
        *(bf16x8*)&As[row * 136 + cg * 8] = o.v8;
    }
    __syncthreads();   // As visible to all waves

    // hoist A fragments (invariant across col phases)
    bf16x8 a1[4];
    #pragma unroll
    for (int ksi = 0; ksi < 4; ++ksi)
        a1[ksi] = *(const bf16x8*)&As[(wave * 16 + lrow) * 136 + ksi * 32 + kg8];

    for (int c6 = 0; c6 < 6; ++c6) {
        // stage col tile c6: 16 x 1KB chunks, 4 waves x 4 issues
        const bf16* Bg = QWs + c6 * 8192;
        #pragma unroll
        for (int j = 0; j < 4; ++j) {
            int chunk = wave * 4 + j;                 // 0..15, wave-uniform
            gload16(Bg + chunk * 512 + lane * 8, Bt + chunk * 512);
        }
        __syncthreads();       // drains the async loads

        f32x4 acc[4] = {};
        #pragma unroll
        for (int ksi = 0; ksi < 4; ++ksi) {
            int k0 = ksi * 32 + kg8;
            #pragma unroll
            for (int ct = 0; ct < 4; ++ct) {
                bf16x8 bb = *(const bf16x8*)&Bt[(ct * 16 + lrow) * 128 + (k0 ^ swzq)];
                acc[ct] = mfma16(a1[ksi], bb, acc[ct]);
            }
        }
        #pragma unroll
        for (int ct = 0; ct < 4; ++ct) {
            int gcol = c6 * 64 + ct * 16 + lrow;
            float bv = bias[gcol];
            #pragma unroll
            for (int r2 = 0; r2 < 4; ++r2) {
                int grow = row0 + wave * 16 + g4 + r2;
                out[(size_t)grow * 384 + gcol] = f2b(acc[ct][r2] + bv);
            }
        }
        __syncthreads();       // all reads of Bt done before next overwrite
    }
}

// ---------------------------------------------------------------------------
// K3: windowed attention, one block per (window, head)
// ---------------------------------------------------------------------------
__global__ __launch_bounds__(256) void k_attn(const bf16* __restrict__ qkv,
        const float* __restrict__ BT, bf16* __restrict__ aout) {
    __shared__ __align__(16) bf16 qs[112 * 40];
    __shared__ __align__(16) bf16 ksm[112 * 40];
    __shared__ __align__(16) bf16 vt[32 * 136];
    __shared__ __align__(16) bf16 ps[64 * 136];
    __shared__ signed char trg[112];

    int tid = threadIdx.x;
    int bn = blockIdx.x, h = blockIdx.y;
    int wrw = bn & 127;
    int dB = wrw >> 6, hB = (wrw >> 3) & 7, wB = wrw & 7;

    { // zero LDS (pads matter)
        uint32_t* z1 = (uint32_t*)qs;
        uint32_t* z2 = (uint32_t*)ksm;
        for (int i = tid; i < 2240; i += 256) { z1[i] = 0u; z2[i] = 0u; }
        uint32_t* z3 = (uint32_t*)vt;
        for (int i = tid; i < 2176; i += 256) z3[i] = 0u;
        uint32_t* z4 = (uint32_t*)ps;
        for (int i = tid; i < 4352; i += 256) z4[i] = 0u;
    }
    if (tid < 112) {
        int n = tid < 98 ? tid : 97;
        int dd = n >= 49, rem = n - dd * 49;
        int hh = rem / 7, ww2 = rem - hh * 7;
        int dp = dB * 2 + dd, hp = hB * 7 + hh, wp = wB * 7 + ww2;
        int rd = dp < 2 ? 0 : (dp == 2 ? 1 : 2);
        int rh = hp < 49 ? 0 : (hp < 53 ? 1 : 2);
        int rw = wp < 49 ? 0 : (wp < 53 ? 1 : 2);
        trg[tid] = (signed char)(rd * 9 + rh * 3 + rw);
    }
    __syncthreads();
    const size_t base = (size_t)bn * 98 * 384 + h * 32;
    for (int ch = tid; ch < 1176; ch += 256) {
        int mat = ch / 392;
        int rem = ch - mat * 392;
        int row = rem >> 2, cg = rem & 3;
        uint4 v = *(const uint4*)&qkv[base + (size_t)row * 384 + mat * 128 + cg * 8];
        if (mat == 0)      *(uint4*)&qs[row * 40 + cg * 8] = v;
        else if (mat == 1) *(uint4*)&ksm[row * 40 + cg * 8] = v;
        else {
            const bf16* pv = (const bf16*)&v;
            #pragma unroll
            for (int j = 0; j < 8; ++j) vt[(cg * 8 + j) * 136 + row] = pv[j];
        }
    }
    __syncthreads();

    int wave = tid >> 6, lane = tid & 63;
    int lrow = lane & 15, kg8 = (lane >> 4) * 8, g4 = (lane >> 4) * 4;

    for (int rt = wave; rt < 7; rt += 4) {
        f32x4 sacc[7];
        bf16x8 qa = *(const bf16x8*)&qs[(rt * 16 + lrow) * 40 + kg8];
        #pragma unroll
        for (int ct = 0; ct < 7; ++ct) {
            bf16x8 kb = *(const bf16x8*)&ksm[(ct * 16 + lrow) * 40 + kg8];
            f32x4 z = {};
            sacc[ct] = mfma16(qa, kb, z);
        }
        #pragma unroll
        for (int r2 = 0; r2 < 4; ++r2) {
            int grow = rt * 16 + g4 + r2;
            int mi = grow < 98 ? grow : 97;
            int mrg = trg[mi];
            const float* btrow = &BT[((size_t)h * 98 + mi) * 98];
            float val[7];
            float mx = -1e30f;
            #pragma unroll
            for (int ct = 0; ct < 7; ++ct) {
                int jc = ct * 16 + lrow;
                int jj = jc < 98 ? jc : 97;
                float bias = btrow[jj];
                float mv = (mrg != (int)trg[jj]) ? -100.f : 0.f;
                float v = sacc[ct][r2] * SCALE + bias + mv;
                if (jc >= 98) v = -1e30f;
                val[ct] = v;
                mx = fmaxf(mx, v);
            }
            #pragma unroll
            for (int m = 1; m < 16; m <<= 1) mx = fmaxf(mx, __shfl_xor(mx, m));
            float sum = 0.f;
            #pragma unroll
            for (int ct = 0; ct < 7; ++ct) { val[ct] = __expf(val[ct] - mx); sum += val[ct]; }
            #pragma unroll
            for (int m = 1; m < 16; m <<= 1) sum += __shfl_xor(sum, m);
            float inv = 1.f / sum;
            #pragma unroll
            for (int ct = 0; ct < 7; ++ct)
                ps[(wave * 16 + g4 + r2) * 136 + ct * 16 + lrow] = f2b(val[ct] * inv);
        }
        // PV: this wave reads only the P rows it just wrote (same-wave LDS order)
        #pragma unroll
        for (int ct = 0; ct < 2; ++ct) {
            f32x4 oacc = {};
            #pragma unroll
            for (int ksi = 0; ksi < 4; ++ksi) {
                bf16x8 pa = *(const bf16x8*)&ps[(wave * 16 + lrow) * 136 + ksi * 32 + kg8];
                bf16x8 vb = *(const bf16x8*)&vt[(ct * 16 + lrow) * 136 + ksi * 32 + kg8];
                oacc = mfma16(pa, vb, oacc);
            }
            #pragma unroll
            for (int r2 = 0; r2 < 4; ++r2) {
                int grow = rt * 16 + g4 + r2;
                if (grow < 98)
                    aout[((size_t)bn * 98 + grow) * 128 + h * 32 + ct * 16 + lrow] =
                        f2b(oacc[r2]);
            }
        }
    }
}

// ---------------------------------------------------------------------------
// K4: proj GEMM + window reverse + unshift + residual + LN2
//   x1 stored bf16 (residual); h2 bf16.
// ---------------------------------------------------------------------------
__global__ __launch_bounds__(256) void k_proj(const bf16* __restrict__ A,
        const bf16* __restrict__ PW, const float* __restrict__ pb,
        const float* __restrict__ x, const float* __restrict__ g2,
        const float* __restrict__ be2,
        bf16* __restrict__ x1, bf16* __restrict__ h2) {
    __shared__ __align__(16) bf16 As[64 * 136];
    __shared__ __align__(16) bf16 Bt[128 * 136];
    int tid = threadIdx.x;
    int row0 = blockIdx.x * 64;
    #pragma unroll
    for (int p = 0; p < 4; ++p) {
        int vi = tid + p * 256;
        int row = vi >> 4, cg = vi & 15;
        *(uint4*)&As[row * 136 + cg * 8] =
            *(const uint4*)&A[(size_t)(row0 + row) * 128 + cg * 8];
    }
    #pragma unroll
    for (int p = 0; p < 8; ++p) {
        int vi = tid + p * 256;
        int row = vi >> 4, cg = vi & 15;
        *(uint4*)&Bt[row * 136 + cg * 8] =
            *(const uint4*)&PW[(size_t)row * 128 + cg * 8];
    }
    __syncthreads();
    int wave = tid >> 6, lane = tid & 63;
    int lrow = lane & 15, kg8 = (lane >> 4) * 8, g4 = (lane >> 4) * 4;
    f32x4 acc[8] = {};
    #pragma unroll
    for (int ksi = 0; ksi < 4; ++ksi) {
        bf16x8 a = *(const bf16x8*)&As[(wave * 16 + lrow) * 136 + ksi * 32 + kg8];
        #pragma unroll
        for (int ct = 0; ct < 8; ++ct) {
            bf16x8 bb = *(const bf16x8*)&Bt[(ct * 16 + lrow) * 136 + ksi * 32 + kg8];
            acc[ct] = mfma16(a, bb, acc[ct]);
        }
    }
    #pragma unroll
    for (int r2 = 0; r2 < 4; ++r2) {
        int rwin = row0 + wave * 16 + g4 + r2;
        int bn = rwin / 98, n = rwin - bn * 98;
        int b = bn >> 7, wr2 = bn & 127;
        int dB = wr2 >> 6, hB = (wr2 >> 3) & 7, wB = wr2 & 7;
        int dd = n >= 49, rem = n - dd * 49;
        int hh = rem / 7, ww2 = rem - hh * 7;
        int dp = dB * 2 + dd, hp = hB * 7 + hh, wp = wB * 7 + ww2;
        int d2 = (dp + 1) & 3;
        int hv = hp + 3; if (hv >= 56) hv -= 56;
        int wv = wp + 3; if (wv >= 56) wv -= 56;
        size_t dst = ((size_t)(b * 4 + d2) * 56 + hv) * 56 + wv;
        float vals[8], s = 0.f, sq = 0.f;
        #pragma unroll
        for (int ct = 0; ct < 8; ++ct) {
            int col = ct * 16 + lrow;
            float v = acc[ct][r2] + pb[col] + x[dst * 128 + col];
            vals[ct] = v; s += v; sq += v * v;
        }
        #pragma unroll
        for (int m = 1; m < 16; m <<= 1) { s += __shfl_xor(s, m); sq += __shfl_xor(sq, m); }
        float mean = s * (1.f / 128.f);
        float var = sq * (1.f / 128.f) - mean * mean;
        float rstd = rsqrtf(var + EPS);
        #pragma unroll
        for (int ct = 0; ct < 8; ++ct) {
            int col = ct * 16 + lrow;
            x1[dst * 128 + col] = f2b(vals[ct]);
            h2[dst * 128 + col] = f2b((vals[ct] - mean) * rstd * g2[col] + be2[col]);
        }
    }
}

// ---------------------------------------------------------------------------
// K5: fused MLP  out = x1 + gelu(h2@fc1+b1)@fc2 + b2     (out f32)
//   EXACT replay-proven r7 structure: 512 threads, 128-row tile, 8 phases of
//   64 hiddens, single 32KB weight stage via global_load_lds, two barriers
//   per phase.  A in registers.  50.4KB LDS -> 3 blocks/CU.
// ---------------------------------------------------------------------------
__global__ __launch_bounds__(512) void k_mlp(const bf16* __restrict__ h2,
        const bf16* __restrict__ W1s, const float* __restrict__ b1,
        const bf16* __restrict__ W2s, const float* __restrict__ b2v,
        const bf16* __restrict__ x1, float* __restrict__ out) {
    __shared__ __align__(16) bf16 W1b[8192];      // [64 hid][128 k] swizzled
    __shared__ __align__(16) bf16 W2b[8192];      // [128 out][64 k] swizzled
    __shared__ __align__(16) bf16 Ts[128 * 72];
    int tid = threadIdx.x;
    int row0 = blockIdx.x * 128;
    int wave = tid >> 6, lane = tid & 63;
    int lrow = lane & 15, kg8 = (lane >> 4) * 8, g4 = (lane >> 4) * 4;
    int swz = (lrow & 7) << 3;

    // A fragments from global; each wave owns rows wave*16 .. wave*16+15
    bf16x8 a1[4];
    const bf16* arow = &h2[(size_t)(row0 + wave * 16 + lrow) * 128];
    #pragma unroll
    for (int ksi = 0; ksi < 4; ++ksi)
        a1[ksi] = *(const bf16x8*)&arow[ksi * 32 + kg8];

    f32x4 oacc[8] = {};
    for (int hc = 0; hc < 8; ++hc) {
        // stage W1(hc)+W2(hc): 32 x 1KB chunks, 8 waves x 4 issues
        const bf16* W1g = W1s + hc * 8192;
        const bf16* W2g = W2s + hc * 8192;
        #pragma unroll
        for (int j = 0; j < 4; ++j) {
            int chunk = wave + j * 8;             // 0..31, wave-uniform
            if (chunk < 16) gload16(W1g + chunk * 512 + lane * 8, W1b + chunk * 512);
            else            gload16(W2g + (chunk - 16) * 512 + lane * 8, W2b + (chunk - 16) * 512);
        }
        __syncthreads();       // barrier waitcnt drains the async loads

        // fc1: 16 rows x 64 hidden per wave, K=128
        f32x4 tacc[4] = {};
        #pragma unroll
        for (int ksi = 0; ksi < 4; ++ksi) {
            int k0 = ksi * 32 + kg8;
            #pragma unroll
            for (int ct = 0; ct < 4; ++ct) {
                bf16x8 bb = *(const bf16x8*)&W1b[(ct * 16 + lrow) * 128 + (k0 ^ swz)];
                tacc[ct] = mfma16(a1[ksi], bb, tacc[ct]);
            }
        }
        // gelu -> Ts (wave-private rows)
        #pragma unroll
        for (int ct = 0; ct < 4; ++ct) {
            int hcol = hc * 64 + ct * 16 + lrow;
            float bb = b1[hcol];
            #pragma unroll
            for (int r2 = 0; r2 < 4; ++r2) {
                float t = gelu_f(tacc[ct][r2] + bb);
                Ts[(wave * 16 + g4 + r2) * 72 + ct * 16 + lrow] = f2b(t);
            }
        }
        // fc2: accumulate 16 rows x 128 out per wave, K=64
        #pragma unroll
        for (int ksi = 0; ksi < 2; ++ksi) {
            int k0 = ksi * 32 + kg8;
            bf16x8 a = *(const bf16x8*)&Ts[(wave * 16 + lrow) * 72 + k0];
            #pragma unroll
            for (int ct = 0; ct < 8; ++ct) {
                bf16x8 bb = *(const bf16x8*)&W2b[(ct * 16 + lrow) * 64 + (k0 ^ swz)];
                oacc[ct] = mfma16(a, bb, oacc[ct]);
            }
        }
        __syncthreads();       // all waves done reading W before next stage
    }
    #pragma unroll
    for (int ct = 0; ct < 8; ++ct) {
        int col = ct * 16 + lrow;
        float bb = b2v[col];
        #pragma unroll
        for (int r2 = 0; r2 < 4; ++r2) {
            size_t grow = (size_t)row0 + wave * 16 + g4 + r2;
            out[grow * 128 + col] = oacc[ct][r2] + bb + b2f(x1[grow * 128 + col]);
        }
    }
}

// ---------------------------------------------------------------------------
extern "C" void kernel_launch(void* const* d_in, const int* in_sizes, int n_in,
                              void* d_out, int out_size, void* d_ws, size_t ws_size,
                              hipStream_t stream) {
    (void)in_sizes; (void)n_in; (void)out_size; (void)ws_size;
    const float* x      = (const float*)d_in[0];
    const float* n1g    = (const float*)d_in[1];
    const float* n1b    = (const float*)d_in[2];
    const float* qkv_w  = (const float*)d_in[3];
    const float* qkv_b  = (const float*)d_in[4];
    const float* rpb    = (const float*)d_in[5];
    const float* proj_w = (const float*)d_in[6];
    const float* proj_b = (const float*)d_in[7];
    const float* n2g    = (const float*)d_in[8];
    const float* n2b    = (const float*)d_in[9];
    const float* fc1_w  = (const float*)d_in[10];
    const float* fc1_b  = (const float*)d_in[11];
    const float* fc2_w  = (const float*)d_in[12];
    const float* fc2_b  = (const float*)d_in[13];
    float* outp = (float*)d_out;

    char* ws = (char*)d_ws;
    constexpr size_t S = (size_t)MTOT * 128 * 2;   // 25,690,112 B (one bf16 token-plane)
    bf16*  qkvbuf = (bf16*)(ws + S);      // [S, 4S)   qkv (bf16)
    bf16*  aout   = (bf16*)ws;            // [0, S)
    bf16*  x1     = (bf16*)(ws + S);      // [S, 2S)   bf16 residual (after attn)
    bf16*  h2     = (bf16*)(ws + 3 * S);  // [3S, 4S)
    // weight area after 4S
    char* wp_ = ws + 4 * S;
    bf16*  QWs = (bf16*)wp_;                      // 384*128*2 = 98304
    bf16*  PW  = (bf16*)(wp_ + 98304);            // 128*128*2 = 32768
    bf16*  W1s = (bf16*)(wp_ + 98304 + 32768);    // 131072 (8 tiles)
    bf16*  W2s = (bf16*)(wp_ + 98304 + 32768 + 131072);  // 131072 (8 tiles)
    float* BTb = (float*)(wp_ + 98304 + 32768 + 131072 + 131072); // 4*98*98*4

    k_prep <<<192, 256, 0, stream>>>(qkv_w, proj_w, fc1_w, fc2_w, rpb, QWs, PW, W1s, W2s, BTb);
    k_qkvln<<<MTOT / 64, 256, 0, stream>>>(x, n1g, n1b, QWs, qkv_b, qkvbuf);
    k_attn <<<dim3(BNWIN, 4), 256, 0, stream>>>(qkvbuf, BTb, aout);
    k_proj <<<MTOT / 64, 256, 0, stream>>>(aout, PW, proj_b, x, n2g, n2b, x1, h2);
    k_mlp  <<<MTOT / 128, 512, 0, stream>>>(h2, W1s, fc1_b, W2s, fc2_b, x1, outp);
}

// Round 13
// 192.739 us; speedup vs baseline: 1.1718x; 1.0266x over previous
//
#include <hip/hip_runtime.h>
#include <hip/hip_bf16.h>
#include <cstdint>
#include <cstddef>

using bf16 = __hip_bfloat16;
typedef __bf16 bf16x8 __attribute__((ext_vector_type(8)));
typedef float f32x4 __attribute__((ext_vector_type(4)));
typedef float f32x16 __attribute__((ext_vector_type(16)));

#define DEV static __device__ __forceinline__

DEV bf16 f2b(float x) { return __float2bfloat16(x); }
DEV float b2f(bf16 x) { return __bfloat162float(x); }
DEV f32x4 mfma16(bf16x8 a, bf16x8 b, f32x4 c) {
    return __builtin_amdgcn_mfma_f32_16x16x32_bf16(a, b, c, 0, 0, 0);
}
DEV f32x16 mfma32(bf16x8 a, bf16x8 b, f32x16 c) {
    return __builtin_amdgcn_mfma_f32_32x32x16_bf16(a, b, c, 0, 0, 0);
}
// tanh-form GELU as x*sigmoid(2u), u = 0.79788456x + 0.03567741x^3.
DEV float gelu_f(float x) {
    float u2 = x * x;
    float u = x * (0.7978845608028654f + 0.0356774081363001f * u2);
    float s = 1.f / (1.f + __expf(-2.f * u));
    return x * s;
}
// async 16B/lane global->LDS copy (LDS dest = uniform base + lane*16)
DEV void gload16(const bf16* g, bf16* l) {
    __builtin_amdgcn_global_load_lds(
        (const __attribute__((address_space(1))) unsigned int*)g,
        (__attribute__((address_space(3))) unsigned int*)l, 16, 0, 0);
}

// problem constants
constexpr int NTOK = 98;           // tokens per window (2*7*7)
constexpr int BNWIN = 1024;        // 8 * 128 windows
constexpr int MTOT = BNWIN * NTOK; // 100352
constexpr float SCALE = 0.17677669529663687f; // 32^-0.5
constexpr float EPS = 1e-5f;

// ---------------------------------------------------------------------------
// K0: one-time prep — bf16 transposed + swizzled weights + bias table
//   QWs: 6 tiles [64 n][128 k],  k ^= (n&7)<<3
//   PW  [128][128] = proj_w^T (linear)
//   W1s: 8 tiles [64 hid][128 k], k ^= (r&7)<<3
//   W2s: 8 tiles [128 out][64 k], k ^= (c&7)<<3
//   BT [4][98][98]
// ---------------------------------------------------------------------------
__global__ __launch_bounds__(256) void k_prep(const float* __restrict__ qkv_w,
        const float* __restrict__ proj_w, const float* __restrict__ fc1_w,
        const float* __restrict__ fc2_w, const float* __restrict__ rpb,
        bf16* __restrict__ QWs, bf16* __restrict__ PW,
        bf16* __restrict__ W1, bf16* __restrict__ W2, float* __restrict__ BT) {
    int tid = blockIdx.x * 256 + threadIdx.x;
    int stride = gridDim.x * 256;
    for (int i = tid; i < 384 * 128; i += stride) {   // QWs tiles
        int t = i >> 13, r = (i >> 7) & 63, kswz = i & 127;
        int k = kswz ^ ((r & 7) << 3);
        QWs[i] = f2b(qkv_w[(size_t)k * 384 + t * 64 + r]);
    }
    for (int i = tid; i < 128 * 128; i += stride) {
        int n = i >> 7, k = i & 127;
        PW[i] = f2b(proj_w[k * 128 + n]);
    }
    for (int i = tid; i < 512 * 128; i += stride) {   // W1s tiles
        int t = i >> 13, r = (i >> 7) & 63, kswz = i & 127;
        int k = kswz ^ ((r & 7) << 3);
        W1[i] = f2b(fc1_w[(size_t)k * 512 + t * 64 + r]);
    }
    for (int i = tid; i < 512 * 128; i += stride) {   // W2s tiles
        int t = i >> 13, c = (i >> 6) & 127, kswz = i & 63;
        int kk = kswz ^ ((c & 7) << 3);               // < 64, in range
        W2[i] = f2b(fc2_w[(size_t)(t * 64 + kk) * 128 + c]);
    }
    for (int i = tid; i < 4 * 98 * 98; i += stride) {
        int h = i / 9604, r = i - h * 9604;
        int ii = r / 98, jj = r - ii * 98;
        int di = ii >= 49, ri = ii - di * 49, hi = ri / 7, wi = ri - hi * 7;
        int dj = jj >= 49, rj = jj - dj * 49, hj = rj / 7, wj = rj - hj * 7;
        int bidx = (di - dj + 1) * 169 + (hi - hj + 6) * 13 + (wi - wj + 6);
        BT[i] = rpb[bidx * 4 + h];
    }
}

// ---------------------------------------------------------------------------
// K2: fused LN1 + shift + window-partition + QKV GEMM
//   Single Bt buffer; stage -> barrier -> compute -> barrier per col phase.
// ---------------------------------------------------------------------------
__global__ __launch_bounds__(256) void k_qkvln(const float* __restrict__ x,
        const float* __restrict__ g, const float* __restrict__ be,
        const bf16* __restrict__ QWs, const float* __restrict__ bias,
        bf16* __restrict__ out) {
    __shared__ __align__(16) bf16 As[64 * 136];
    __shared__ __align__(16) bf16 Bt[64 * 128];
    int tid = threadIdx.x;
    int row0 = blockIdx.x * 64;
    int wave = tid >> 6, lane = tid & 63;
    int lrow = lane & 15, kg8 = (lane >> 4) * 8, g4 = (lane >> 4) * 4;
    int swzq = (lrow & 7) << 3;

    // ---- LN1 + gather staging: 4 phases, 16 threads per row ----
    #pragma unroll
    for (int p = 0; p < 4; ++p) {
        int vi = tid + p * 256;
        int row = vi >> 4, cg = vi & 15;
        int r = row0 + row;
        int bn = r / 98, n = r - bn * 98;
        int b = bn >> 7, wr = bn & 127;
        int dB = wr >> 6, hB = (wr >> 3) & 7, wB = wr & 7;
        int dd = (n >= 49), rem = n - dd * 49;
        int hh = rem / 7, ww = rem - hh * 7;
        int dp = dB * 2 + dd, hp = hB * 7 + hh, wp = wB * 7 + ww;
        int ds = (dp + 1) & 3;
        int hs = hp + 3; if (hs >= 56) hs -= 56;
        int wsv = wp + 3; if (wsv >= 56) wsv -= 56;
        size_t src = ((size_t)((b * 4 + ds) * 56 + hs) * 56 + wsv) * 128 + cg * 8;
        float4 v0 = *(const float4*)&x[src];
        float4 v1 = *(const float4*)&x[src + 4];
        float s = v0.x + v0.y + v0.z + v0.w + v1.x + v1.y + v1.z + v1.w;
        float sq = v0.x*v0.x + v0.y*v0.y + v0.z*v0.z + v0.w*v0.w
                 + v1.x*v1.x + v1.y*v1.y + v1.z*v1.z + v1.w*v1.w;
        #pragma unroll
        for (int m = 1; m < 16; m <<= 1) { s += __shfl_xor(s, m); sq += __shfl_xor(sq, m); }
        float mean = s * (1.f / 128.f);
        float var = sq * (1.f / 128.f) - mean * mean;
        float rstd = rsqrtf(var + EPS);
        float4 g0 = *(const float4*)&g[cg * 8], g1 = *(const float4*)&g[cg * 8 + 4];
        float4 e0 = *(const float4*)&be[cg * 8], e1 = *(const float4*)&be[cg * 8 + 4];
        union { bf16x8 v8; bf16 h[8]; } o;
        o.h[0] = f2b((v0.x - mean) * rstd * g0.x + e0.x);
        o.h[1] = f2b((v0.y - mean) * rstd * g0.y + e0.y);
        o.h[2] = f2b((v0.z - mean) * rstd * g0.z + e0.z);
        o.h[3] = f2b((v0.w - mean) * rstd * g0.w + e0.w);
        o.h[4] = f2b((v1.x - mean) * rstd * g1.x + e1.x);
        o.h[5] = f2b((v1.y - mean) * rstd * g1.y + e1.y);
        o.h[6] = f2b((v1.z - mean) * rstd * g1.z + e1.z);
        o.h[7] = f2b((v1.w - mean) * rstd * g1.w + e1.w);
        *(bf16x8*)&As[row * 136 + cg * 8] = o.v8;
    }
    __syncthreads();   // As visible to all waves

    // hoist A fragments (invariant across col phases)
    bf16x8 a1[4];
    #pragma unroll
    for (int ksi = 0; ksi < 4; ++ksi)
        a1[ksi] = *(const bf16x8*)&As[(wave * 16 + lrow) * 136 + ksi * 32 + kg8];

    for (int c6 = 0; c6 < 6; ++c6) {
        // stage col tile c6: 16 x 1KB chunks, 4 waves x 4 issues
        const bf16* Bg = QWs + c6 * 8192;
        #pragma unroll
        for (int j = 0; j < 4; ++j) {
            int chunk = wave * 4 + j;                 // 0..15, wave-uniform
            gload16(Bg + chunk * 512 + lane * 8, Bt + chunk * 512);
        }
        __syncthreads();       // drains the async loads

        f32x4 acc[4] = {};
        #pragma unroll
        for (int ksi = 0; ksi < 4; ++ksi) {
            int k0 = ksi * 32 + kg8;
            #pragma unroll
            for (int ct = 0; ct < 4; ++ct) {
                bf16x8 bb = *(const bf16x8*)&Bt[(ct * 16 + lrow) * 128 + (k0 ^ swzq)];
                acc[ct] = mfma16(a1[ksi], bb, acc[ct]);
            }
        }
        #pragma unroll
        for (int ct = 0; ct < 4; ++ct) {
            int gcol = c6 * 64 + ct * 16 + lrow;
            float bv = bias[gcol];
            #pragma unroll
            for (int r2 = 0; r2 < 4; ++r2) {
                int grow = row0 + wave * 16 + g4 + r2;
                out[(size_t)grow * 384 + gcol] = f2b(acc[ct][r2] + bv);
            }
        }
        __syncthreads();       // all reads of Bt done before next overwrite
    }
}

// ---------------------------------------------------------------------------
// K3: windowed attention, one block per (window, head)
// ---------------------------------------------------------------------------
__global__ __launch_bounds__(256) void k_attn(const bf16* __restrict__ qkv,
        const float* __restrict__ BT, bf16* __restrict__ aout) {
    __shared__ __align__(16) bf16 qs[112 * 40];
    __shared__ __align__(16) bf16 ksm[112 * 40];
    __shared__ __align__(16) bf16 vt[32 * 136];
    __shared__ __align__(16) bf16 ps[64 * 136];
    __shared__ signed char trg[112];

    int tid = threadIdx.x;
    int bn = blockIdx.x, h = blockIdx.y;
    int wrw = bn & 127;
    int dB = wrw >> 6, hB = (wrw >> 3) & 7, wB = wrw & 7;

    { // zero LDS (pads matter)
        uint32_t* z1 = (uint32_t*)qs;
        uint32_t* z2 = (uint32_t*)ksm;
        for (int i = tid; i < 2240; i += 256) { z1[i] = 0u; z2[i] = 0u; }
        uint32_t* z3 = (uint32_t*)vt;
        for (int i = tid; i < 2176; i += 256) z3[i] = 0u;
        uint32_t* z4 = (uint32_t*)ps;
        for (int i = tid; i < 4352; i += 256) z4[i] = 0u;
    }
    if (tid < 112) {
        int n = tid < 98 ? tid : 97;
        int dd = n >= 49, rem = n - dd * 49;
        int hh = rem / 7, ww2 = rem - hh * 7;
        int dp = dB * 2 + dd, hp = hB * 7 + hh, wp = wB * 7 + ww2;
        int rd = dp < 2 ? 0 : (dp == 2 ? 1 : 2);
        int rh = hp < 49 ? 0 : (hp < 53 ? 1 : 2);
        int rw = wp < 49 ? 0 : (wp < 53 ? 1 : 2);
        trg[tid] = (signed char)(rd * 9 + rh * 3 + rw);
    }
    __syncthreads();
    const size_t base = (size_t)bn * 98 * 384 + h * 32;
    for (int ch = tid; ch < 1176; ch += 256) {
        int mat = ch / 392;
        int rem = ch - mat * 392;
        int row = rem >> 2, cg = rem & 3;
        uint4 v = *(const uint4*)&qkv[base + (size_t)row * 384 + mat * 128 + cg * 8];
        if (mat == 0)      *(uint4*)&qs[row * 40 + cg * 8] = v;
        else if (mat == 1) *(uint4*)&ksm[row * 40 + cg * 8] = v;
        else {
            const bf16* pv = (const bf16*)&v;
            #pragma unroll
            for (int j = 0; j < 8; ++j) vt[(cg * 8 + j) * 136 + row] = pv[j];
        }
    }
    __syncthreads();

    int wave = tid >> 6, lane = tid & 63;
    int lrow = lane & 15, kg8 = (lane >> 4) * 8, g4 = (lane >> 4) * 4;

    for (int rt = wave; rt < 7; rt += 4) {
        f32x4 sacc[7];
        bf16x8 qa = *(const bf16x8*)&qs[(rt * 16 + lrow) * 40 + kg8];
        #pragma unroll
        for (int ct = 0; ct < 7; ++ct) {
            bf16x8 kb = *(const bf16x8*)&ksm[(ct * 16 + lrow) * 40 + kg8];
            f32x4 z = {};
            sacc[ct] = mfma16(qa, kb, z);
        }
        #pragma unroll
        for (int r2 = 0; r2 < 4; ++r2) {
            int grow = rt * 16 + g4 + r2;
            int mi = grow < 98 ? grow : 97;
            int mrg = trg[mi];
            const float* btrow = &BT[((size_t)h * 98 + mi) * 98];
            float val[7];
            float mx = -1e30f;
            #pragma unroll
            for (int ct = 0; ct < 7; ++ct) {
                int jc = ct * 16 + lrow;
                int jj = jc < 98 ? jc : 97;
                float bias = btrow[jj];
                float mv = (mrg != (int)trg[jj]) ? -100.f : 0.f;
                float v = sacc[ct][r2] * SCALE + bias + mv;
                if (jc >= 98) v = -1e30f;
                val[ct] = v;
                mx = fmaxf(mx, v);
            }
            #pragma unroll
            for (int m = 1; m < 16; m <<= 1) mx = fmaxf(mx, __shfl_xor(mx, m));
            float sum = 0.f;
            #pragma unroll
            for (int ct = 0; ct < 7; ++ct) { val[ct] = __expf(val[ct] - mx); sum += val[ct]; }
            #pragma unroll
            for (int m = 1; m < 16; m <<= 1) sum += __shfl_xor(sum, m);
            float inv = 1.f / sum;
            #pragma unroll
            for (int ct = 0; ct < 7; ++ct)
                ps[(wave * 16 + g4 + r2) * 136 + ct * 16 + lrow] = f2b(val[ct] * inv);
        }
        // PV: this wave reads only the P rows it just wrote (same-wave LDS order)
        #pragma unroll
        for (int ct = 0; ct < 2; ++ct) {
            f32x4 oacc = {};
            #pragma unroll
            for (int ksi = 0; ksi < 4; ++ksi) {
                bf16x8 pa = *(const bf16x8*)&ps[(wave * 16 + lrow) * 136 + ksi * 32 + kg8];
                bf16x8 vb = *(const bf16x8*)&vt[(ct * 16 + lrow) * 136 + ksi * 32 + kg8];
                oacc = mfma16(pa, vb, oacc);
            }
            #pragma unroll
            for (int r2 = 0; r2 < 4; ++r2) {
                int grow = rt * 16 + g4 + r2;
                if (grow < 98)
                    aout[((size_t)bn * 98 + grow) * 128 + h * 32 + ct * 16 + lrow] =
                        f2b(oacc[r2]);
            }
        }
    }
}

// ---------------------------------------------------------------------------
// K4: proj GEMM + window reverse + unshift + residual + LN2
//   x1 stored bf16 (residual); h2 bf16.
// ---------------------------------------------------------------------------
__global__ __launch_bounds__(256) void k_proj(const bf16* __restrict__ A,
        const bf16* __restrict__ PW, const float* __restrict__ pb,
        const float* __restrict__ x, const float* __restrict__ g2,
        const float* __restrict__ be2,
        bf16* __restrict__ x1, bf16* __restrict__ h2) {
    __shared__ __align__(16) bf16 As[64 * 136];
    __shared__ __align__(16) bf16 Bt[128 * 136];
    int tid = threadIdx.x;
    int row0 = blockIdx.x * 64;
    #pragma unroll
    for (int p = 0; p < 4; ++p) {
        int vi = tid + p * 256;
        int row = vi >> 4, cg = vi & 15;
        *(uint4*)&As[row * 136 + cg * 8] =
            *(const uint4*)&A[(size_t)(row0 + row) * 128 + cg * 8];
    }
    #pragma unroll
    for (int p = 0; p < 8; ++p) {
        int vi = tid + p * 256;
        int row = vi >> 4, cg = vi & 15;
        *(uint4*)&Bt[row * 136 + cg * 8] =
            *(const uint4*)&PW[(size_t)row * 128 + cg * 8];
    }
    __syncthreads();
    int wave = tid >> 6, lane = tid & 63;
    int lrow = lane & 15, kg8 = (lane >> 4) * 8, g4 = (lane >> 4) * 4;
    f32x4 acc[8] = {};
    #pragma unroll
    for (int ksi = 0; ksi < 4; ++ksi) {
        bf16x8 a = *(const bf16x8*)&As[(wave * 16 + lrow) * 136 + ksi * 32 + kg8];
        #pragma unroll
        for (int ct = 0; ct < 8; ++ct) {
            bf16x8 bb = *(const bf16x8*)&Bt[(ct * 16 + lrow) * 136 + ksi * 32 + kg8];
            acc[ct] = mfma16(a, bb, acc[ct]);
        }
    }
    #pragma unroll
    for (int r2 = 0; r2 < 4; ++r2) {
        int rwin = row0 + wave * 16 + g4 + r2;
        int bn = rwin / 98, n = rwin - bn * 98;
        int b = bn >> 7, wr2 = bn & 127;
        int dB = wr2 >> 6, hB = (wr2 >> 3) & 7, wB = wr2 & 7;
        int dd = n >= 49, rem = n - dd * 49;
        int hh = rem / 7, ww2 = rem - hh * 7;
        int dp = dB * 2 + dd, hp = hB * 7 + hh, wp = wB * 7 + ww2;
        int d2 = (dp + 1) & 3;
        int hv = hp + 3; if (hv >= 56) hv -= 56;
        int wv = wp + 3; if (wv >= 56) wv -= 56;
        size_t dst = ((size_t)(b * 4 + d2) * 56 + hv) * 56 + wv;
        float vals[8], s = 0.f, sq = 0.f;
        #pragma unroll
        for (int ct = 0; ct < 8; ++ct) {
            int col = ct * 16 + lrow;
            float v = acc[ct][r2] + pb[col] + x[dst * 128 + col];
            vals[ct] = v; s += v; sq += v * v;
        }
        #pragma unroll
        for (int m = 1; m < 16; m <<= 1) { s += __shfl_xor(s, m); sq += __shfl_xor(sq, m); }
        float mean = s * (1.f / 128.f);
        float var = sq * (1.f / 128.f) - mean * mean;
        float rstd = rsqrtf(var + EPS);
        #pragma unroll
        for (int ct = 0; ct < 8; ++ct) {
            int col = ct * 16 + lrow;
            x1[dst * 128 + col] = f2b(vals[ct]);
            h2[dst * 128 + col] = f2b((vals[ct] - mean) * rstd * g2[col] + be2[col]);
        }
    }
}

// ---------------------------------------------------------------------------
// K5: fused MLP with 32x32x16 MFMA (B-fragment feeds 2x the FLOPs -> LDS
//   bytes/FLOP halved).  256 threads / 4 waves x 32 rows = 128-row tile;
//   8 phases of 64 hiddens; stage->barrier->compute->barrier (replay-proven
//   topology).  LDS 50.4 KB -> 3 blocks/CU.
//   Layouts (m74/m101-verified): A/B: row|col=lane&31, k=(lane>>5)*8+i;
//   C/D: col=lane&31, row=(reg&3)+8*(reg>>2)+4*(lane>>5).
// ---------------------------------------------------------------------------
__global__ __launch_bounds__(256, 3) void k_mlp(const bf16* __restrict__ h2,
        const bf16* __restrict__ W1s, const float* __restrict__ b1,
        const bf16* __restrict__ W2s, const float* __restrict__ b2v,
        const bf16* __restrict__ x1, float* __restrict__ out) {
    __shared__ __align__(16) bf16 W1b[8192];      // [64 hid][128 k] swizzled
    __shared__ __align__(16) bf16 W2b[8192];      // [128 out][64 k] swizzled
    __shared__ __align__(16) bf16 Ts[128 * 72];   // [row][hid-of-phase]
    int tid = threadIdx.x;
    int row0 = blockIdx.x * 128;
    int wave = tid >> 6, lane = tid & 63;
    int l31 = lane & 31, hi = lane >> 5;          // hi in {0,1}
    int swz = (lane & 7) << 3;

    // A fragments from global; wave owns rows wave*32 .. wave*32+31
    bf16x8 a1[8];
    const bf16* arow = &h2[(size_t)(row0 + wave * 32 + l31) * 128 + hi * 8];
    #pragma unroll
    for (int ks = 0; ks < 8; ++ks)
        a1[ks] = *(const bf16x8*)&arow[ks * 16];

    f32x16 oacc[4] = {};
    for (int q = 0; q < 8; ++q) {
        // stage W1(q) 16KB + W2(q) 16KB: 32 x 1KB chunks, 4 waves x 8 issues
        const bf16* W1g = W1s + q * 8192;
        const bf16* W2g = W2s + q * 8192;
        #pragma unroll
        for (int j = 0; j < 8; ++j) {
            int chunk = wave * 8 + j;             // 0..31, wave-uniform
            if (chunk < 16) gload16(W1g + chunk * 512 + lane * 8, W1b + chunk * 512);
            else            gload16(W2g + (chunk - 16) * 512 + lane * 8, W2b + (chunk - 16) * 512);
        }
        __syncthreads();       // barrier waitcnt drains the async loads

        // fc1: 32 rows x 64 hidden per wave, K=128 (8 k-steps of 16)
        f32x16 tacc[2] = {};
        #pragma unroll
        for (int ks = 0; ks < 8; ++ks) {
            int k0 = ks * 16 + hi * 8;
            #pragma unroll
            for (int ht = 0; ht < 2; ++ht) {
                bf16x8 bb = *(const bf16x8*)&W1b[(ht * 32 + l31) * 128 + (k0 ^ swz)];
                tacc[ht] = mfma32(a1[ks], bb, tacc[ht]);
            }
        }
        // gelu + bias -> Ts (wave-private rows)
        #pragma unroll
        for (int ht = 0; ht < 2; ++ht) {
            float bbv = b1[q * 64 + ht * 32 + l31];
            #pragma unroll
            for (int r = 0; r < 16; ++r) {
                int row = (r & 3) + 8 * (r >> 2) + 4 * hi;
                Ts[(wave * 32 + row) * 72 + ht * 32 + l31] =
                    f2b(gelu_f(tacc[ht][r] + bbv));
            }
        }
        // fc2: 32 rows x 128 out per wave, K=64 (4 k-steps of 16)
        #pragma unroll
        for (int ks = 0; ks < 4; ++ks) {
            int k0 = ks * 16 + hi * 8;
            bf16x8 a = *(const bf16x8*)&Ts[(wave * 32 + l31) * 72 + k0];
            #pragma unroll
            for (int ot = 0; ot < 4; ++ot) {
                bf16x8 bb = *(const bf16x8*)&W2b[(ot * 32 + l31) * 64 + (k0 ^ swz)];
                oacc[ot] = mfma32(a, bb, oacc[ot]);
            }
        }
        __syncthreads();       // all waves done reading W before next stage
    }
    // epilogue: out = oacc + b2 + x1
    #pragma unroll
    for (int ot = 0; ot < 4; ++ot) {
        int col = ot * 32 + l31;
        float bbv = b2v[col];
        #pragma unroll
        for (int r = 0; r < 16; ++r) {
            int row = (r & 3) + 8 * (r >> 2) + 4 * hi;
            size_t grow = (size_t)row0 + wave * 32 + row;
            out[grow * 128 + col] = oacc[ot][r] + bbv + b2f(x1[grow * 128 + col]);
        }
    }
}

// ---------------------------------------------------------------------------
extern "C" void kernel_launch(void* const* d_in, const int* in_sizes, int n_in,
                              void* d_out, int out_size, void* d_ws, size_t ws_size,
                              hipStream_t stream) {
    (void)in_sizes; (void)n_in; (void)out_size; (void)ws_size;
    const float* x      = (const float*)d_in[0];
    const float* n1g    = (const float*)d_in[1];
    const float* n1b    = (const float*)d_in[2];
    const float* qkv_w  = (const float*)d_in[3];
    const float* qkv_b  = (const float*)d_in[4];
    const float* rpb    = (const float*)d_in[5];
    const float* proj_w = (const float*)d_in[6];
    const float* proj_b = (const float*)d_in[7];
    const float* n2g    = (const float*)d_in[8];
    const float* n2b    = (const float*)d_in[9];
    const float* fc1_w  = (const float*)d_in[10];
    const float* fc1_b  = (const float*)d_in[11];
    const float* fc2_w  = (const float*)d_in[12];
    const float* fc2_b  = (const float*)d_in[13];
    float* outp = (float*)d_out;

    char* ws = (char*)d_ws;
    constexpr size_t S = (size_t)MTOT * 128 * 2;   // 25,690,112 B (one bf16 token-plane)
    bf16*  qkvbuf = (bf16*)(ws + S);      // [S, 4S)   qkv (bf16)
    bf16*  aout   = (bf16*)ws;            // [0, S)
    bf16*  x1     = (bf16*)(ws + S);      // [S, 2S)   bf16 residual (after attn)
    bf16*  h2     = (bf16*)(ws + 3 * S);  // [3S, 4S)
    // weight area after 4S
    char* wp_ = ws + 4 * S;
    bf16*  QWs = (bf16*)wp_;                      // 384*128*2 = 98304
    bf16*  PW  = (bf16*)(wp_ + 98304);            // 128*128*2 = 32768
    bf16*  W1s = (bf16*)(wp_ + 98304 + 32768);    // 131072 (8 tiles)
    bf16*  W2s = (bf16*)(wp_ + 98304 + 32768 + 131072);  // 131072 (8 tiles)
    float* BTb = (float*)(wp_ + 98304 + 32768 + 131072 + 131072); // 4*98*98*4

    k_prep <<<192, 256, 0, stream>>>(qkv_w, proj_w, fc1_w, fc2_w, rpb, QWs, PW, W1s, W2s, BTb);
    k_qkvln<<<MTOT / 64, 256, 0, stream>>>(x, n1g, n1b, QWs, qkv_b, qkvbuf);
    k_attn <<<dim3(BNWIN, 4), 256, 0, stream>>>(qkvbuf, BTb, aout);
    k_proj <<<MTOT / 64, 256, 0, stream>>>(aout, PW, proj_b, x, n2g, n2b, x1, h2);
    k_mlp  <<<MTOT / 128, 256, 0, stream>>>(h2, W1s, fc1_b, W2s, fc2_b, x1, outp);
}